// Round 10
// baseline (414.277 us; speedup 1.0000x reference)
//
#include <hip/hip_runtime.h>
#include <math.h>

// kNN (B=1024, C=500000, D=64) + inverse-distance weighting, top-50.
// R18: (a) filter epilogue: EXACT wave-OR group screen. R17 PMC arithmetic:
// VALUBusy 29% => ~750 VALU/wave/phase vs ~300 static -> the per-value
// predication (cmpx+cbranch+exec-restore, ~4 ops x 128) dominates. Replace
// with per-4-group: 4 v_cmp (to sgpr masks) + s_or + ONE execz-branch;
// fires only at true wave-hit rate (~23%), unlike R15's conservative fmax
// screen (~50% + extra VALU). Semantics identical (outer skip iff no lane
// has any hit; inner per-value ifs exact).
// (b) qthresh_mfma re-gridded: 64-row chunks -> 256 blocks (was 128 = half
// the CUs idle). Body single-tile, same math, same dsamp layout.
// Filter sync structure = R17 (3-pair ring, depth-2, counted vmcnt(2)
// own-drain BEFORE s_barrier; race-free), unchanged as control.

#define DELTA_SMOOTH 1e-3f
#define K_NEIGH 50
#define MAXCAP 8192
#define NBINS 256
#define MARGIN_T 1.5f      // bf16 dot error margin, both directions (d2 units)
#define MARGIN_Q 26        // select margin in d2q quanta (16 per d2 unit)
#define RPB 1024           // table rows per filter block
#define QTILE 512          // queries per filter block (8 waves x 64)
#define SDEPTH 6           // LDS staging slots per (block,query)
#define LW 768             // select rescore list size
#define CVL 2048           // select LDS candidate cache
#define S_SAMP 8192        // qthresh sample rows
#define T_SAMP 8           // order statistic -> E[count] ~ 488
// fallback (R5/R9-style) constants
#define FSAMPLE 2048
#define FTARGET 6
#define FMARGIN 0.75f
#define FQB 4

typedef __attribute__((ext_vector_type(8))) short short8;
typedef __attribute__((ext_vector_type(4))) float f32x4;
typedef __attribute__((address_space(1))) const unsigned int g_u32;
typedef __attribute__((address_space(3))) unsigned int l_u32;

__device__ __forceinline__ unsigned f2bf(float f) {
  unsigned u = __float_as_uint(f);
  return ((u + 0x7fffu + ((u >> 16) & 1u)) >> 16) & 0xffffu;
}

// ---------------- Kernel 0: table -> bf16 swizzled 64-row tiles + halved norms ----------------
// Row r chunk c (8 bf16 = 16 B) at uint4 index (r>>6)*512 + (r&63)*8 + (c^(r&7)).
// Padded rows (r >= C) get tnh2 = 3e38 so the filter predicate never fires.
__global__ __launch_bounds__(256) void convert_kernel(
    const float* __restrict__ tk, uint4* __restrict__ tkbf,
    float* __restrict__ tnh2, int C, int padded) {
  int t = blockIdx.x * 256 + threadIdx.x;
  int r = t >> 3;
  if (r >= padded) return;
  int c = t & 7;
  int rs = r < C ? r : C - 1;
  const float4* src = (const float4*)(tk + (size_t)rs * 64 + c * 8);
  float4 a = src[0], b = src[1];
  float sq = a.x * a.x + a.y * a.y + a.z * a.z + a.w * a.w
           + b.x * b.x + b.y * b.y + b.z * b.z + b.w * b.w;
  sq += __shfl_xor(sq, 1); sq += __shfl_xor(sq, 2); sq += __shfl_xor(sq, 4);
  if (c == 0) tnh2[r] = (r < C) ? sq * 0.5f : 3e38f;
  uint4 u;
  u.x = f2bf(a.x) | (f2bf(a.y) << 16);
  u.y = f2bf(a.z) | (f2bf(a.w) << 16);
  u.z = f2bf(b.x) | (f2bf(b.y) << 16);
  u.w = f2bf(b.z) | (f2bf(b.w) << 16);
  tkbf[(size_t)(r >> 6) * 512 + (r & 63) * 8 + (c ^ (r & 7))] = u;
}

// ---------------- Kernel 1a: sampled bf16 d2' via MFMA -> u16 store ----------------
// (S_SAMP/64)*2 = 256 blocks: (64-row chunk) x (2 query tiles) -> full machine.
// d2' = 2*(tnh - dot); u16 = clamp((d2' + 128) * 256).
__global__ __launch_bounds__(512, 4) void qthresh_mfma(
    const uint4* __restrict__ tkbf, const float* __restrict__ keys,
    const float* __restrict__ tnh2, unsigned short* __restrict__ dsamp) {
  __shared__ __align__(16) uint4 bstage[512];   // one 64-row tile (8 KB)
  __shared__ float tnh_lds[64];
  int tid = threadIdx.x;
  int qt = blockIdx.x & 1;
  int chunk = blockIdx.x >> 1;       // 0..S_SAMP/64-1
  int qbase = qt * 512;
  int rstart = chunk * 64;
  if (tid < 64) tnh_lds[tid] = tnh2[rstart + tid];
  int lane = tid & 63, wq = tid >> 6, l15 = lane & 15, quad = lane >> 4;
  short8 afrag[4][2];
  #pragma unroll
  for (int mt = 0; mt < 4; ++mt) {
    const float* kp = keys + (size_t)(qbase + wq * 64 + mt * 16 + l15) * 64 + quad * 8;
    #pragma unroll
    for (int s = 0; s < 2; ++s) {
      float4 x = *(const float4*)(kp + s * 32);
      float4 y = *(const float4*)(kp + s * 32 + 4);
      short8 a;
      a[0] = (short)f2bf(x.x); a[1] = (short)f2bf(x.y);
      a[2] = (short)f2bf(x.z); a[3] = (short)f2bf(x.w);
      a[4] = (short)f2bf(y.x); a[5] = (short)f2bf(y.y);
      a[6] = (short)f2bf(y.z); a[7] = (short)f2bf(y.w);
      afrag[mt][s] = a;
    }
  }
  const uint4* gbase = tkbf + (size_t)chunk * 512;
  __builtin_amdgcn_global_load_lds((g_u32*)(gbase + tid),
                                   (l_u32*)((uint4*)&bstage[0] + wq * 64), 16, 0, 0);
  __syncthreads();
  f32x4 zero4 = {0.f, 0.f, 0.f, 0.f};
  const unsigned char* buf = (const unsigned char*)bstage;
  #pragma unroll
  for (int half = 0; half < 2; ++half) {
    short8 b[2][2];
    #pragma unroll
    for (int tt = 0; tt < 2; ++tt) {
      int nloc = half * 32 + tt * 16 + l15;
      #pragma unroll
      for (int s = 0; s < 2; ++s) {
        int c = s * 4 + quad;
        unsigned addr = (unsigned)(nloc * 128 + ((c ^ (nloc & 7)) << 4));
        b[tt][s] = *(const short8*)(buf + addr);
      }
    }
    f32x4 acc[4][2];
    #pragma unroll
    for (int mt = 0; mt < 4; ++mt)
      #pragma unroll
      for (int tt = 0; tt < 2; ++tt) {
        f32x4 a0 = __builtin_amdgcn_mfma_f32_16x16x32_bf16(afrag[mt][0], b[tt][0], zero4, 0, 0, 0);
        acc[mt][tt] = __builtin_amdgcn_mfma_f32_16x16x32_bf16(afrag[mt][1], b[tt][1], a0, 0, 0, 0);
      }
    #pragma unroll
    for (int tt = 0; tt < 2; ++tt) {
      int rloc = half * 32 + tt * 16 + l15;
      float tnh = tnh_lds[rloc];
      int n = rstart + rloc;
      #pragma unroll
      for (int mt = 0; mt < 4; ++mt) {
        #pragma unroll
        for (int r = 0; r < 4; ++r) {
          int ql = wq * 64 + mt * 16 + quad * 4 + r;
          // u16 = (2*(tnh-acc) + 128)*256 = (tnh-acc)*512 + 32768
          int u = (int)fmaf(tnh - acc[mt][tt][r], 512.f, 32768.f);
          u = u < 0 ? 0 : (u > 65535 ? 65535 : u);
          dsamp[(size_t)(qbase + ql) * S_SAMP + n] = (unsigned short)u;
        }
      }
    }
  }
}

// ---------------- Kernel 1b: per-query T-th smallest -> halved threshold ----------------
__global__ __launch_bounds__(256) void qthresh_scan(
    const unsigned short* __restrict__ dsamp, float* __restrict__ thrh,
    int* __restrict__ cnt) {
  int q = blockIdx.x;
  __shared__ unsigned hist[512];
  int tid = threadIdx.x;
  hist[tid] = 0u; hist[tid + 256] = 0u;
  __syncthreads();
  const unsigned short* dp = dsamp + (size_t)q * S_SAMP;
  for (int i = tid; i < S_SAMP; i += 256) atomicAdd(&hist[dp[i] >> 7], 1u);
  __syncthreads();
  if (tid == 0) {
    unsigned cum = 0; int bstar = 511;
    for (int b = 0; b < 512; ++b) {
      cum += hist[b];
      if (cum >= (unsigned)T_SAMP) { bstar = b; break; }
    }
    // bin width 0.5 in d2' space; thr = binUpper + margin; store thr/2
    float thr = (float)(bstar + 1) * 0.5f - 128.f + MARGIN_T;
    thrh[q] = 0.5f * thr;
    cnt[q] = 0;
  }
}

// ---------------- Kernel 2a: 512-thr filter, 3-pair ring, exact-OR screened epilogue ----------------
// 8 waves / 512 queries per block, 2 blocks per 1024-row chunk. Pair p's DMA
// issued during phase p-2 (depth 2); at phase p: s_waitcnt vmcnt(2) drains
// pair p (leaves p+1 in flight) THEN s_barrier publishes it -> race-free with
// a near-free wait. Pair p+2 -> slots of pair p-1 (freed by this barrier).
// MFMA C seeded with -tnh -> acc = dot - tnh; hit <=> acc > -thr (1 cmp).
// Epilogue: per-4-group exact screen = OR of the 4 v_cmp lane-masks + one
// execz branch (fires at true wave-hit rate ~23%), replacing 128 separate
// cmpx/cbranch predications per phase.
__global__ __launch_bounds__(512, 4) void filter_mfma_fast(
    const uint4* __restrict__ tkbf, const float* __restrict__ keys,
    const float* __restrict__ tnh2, const float* __restrict__ thrh,
    int* __restrict__ cnt, unsigned* __restrict__ candi, int C, int cap) {
  __shared__ __align__(16) uint4 bstage[6][512];          // 48 KB: 3 pairs
  __shared__ float tnh_lds[RPB];                          // 4 KB
  __shared__ float thr_lds[QTILE];                        // 2 KB (halved thr)
  __shared__ unsigned scnt[QTILE];                        // 2 KB
  __shared__ unsigned sbuf[QTILE * SDEPTH];               // 12 KB  (total 68 KB)

  int tid = threadIdx.x;
  int qt = blockIdx.x & 1;
  int chunk = blockIdx.x >> 1;
  int qbase = qt * QTILE;
  int rstart = chunk * RPB;

  tnh_lds[tid] = tnh2[rstart + tid];
  tnh_lds[tid + 512] = tnh2[rstart + tid + 512];
  thr_lds[tid] = thrh[qbase + tid];
  scnt[tid] = 0u;

  int lane = tid & 63, wq = tid >> 6, l15 = lane & 15, quad = lane >> 4;

  short8 afrag[4][2];
  #pragma unroll
  for (int mt = 0; mt < 4; ++mt) {
    const float* kp = keys + (size_t)(qbase + wq * 64 + mt * 16 + l15) * 64 + quad * 8;
    #pragma unroll
    for (int s = 0; s < 2; ++s) {
      float4 x = *(const float4*)(kp + s * 32);
      float4 y = *(const float4*)(kp + s * 32 + 4);
      short8 a;
      a[0] = (short)f2bf(x.x); a[1] = (short)f2bf(x.y);
      a[2] = (short)f2bf(x.z); a[3] = (short)f2bf(x.w);
      a[4] = (short)f2bf(y.x); a[5] = (short)f2bf(y.y);
      a[6] = (short)f2bf(y.z); a[7] = (short)f2bf(y.w);
      afrag[mt][s] = a;
    }
  }

  // Drains all prior vector loads (vmcnt ledger clean) + publishes thr_lds.
  __syncthreads();

  // Negated thresholds for this thread's 16 (mt, r) queries -> registers.
  float negthr[4][4];
  #pragma unroll
  for (int mt = 0; mt < 4; ++mt)
    #pragma unroll
    for (int r = 0; r < 4; ++r)
      negthr[mt][r] = -thr_lds[wq * 64 + mt * 16 + quad * 4 + r];

  const uint4* gbase = tkbf + (size_t)(rstart >> 6) * 512;
  const int PAIRS = RPB / 128;   // 8
  // prologue: pairs 0 and 1 in flight (depth 2; pair j -> slots (j%3)*2, +1)
  #pragma unroll
  for (int s = 0; s < 2; ++s)
    __builtin_amdgcn_global_load_lds((g_u32*)(gbase + (size_t)s * 512 + tid),
                                     (l_u32*)((uint4*)&bstage[s][0] + wq * 64), 16, 0, 0);
  #pragma unroll
  for (int s = 0; s < 2; ++s)
    __builtin_amdgcn_global_load_lds((g_u32*)(gbase + (size_t)(2 + s) * 512 + tid),
                                     (l_u32*)((uint4*)&bstage[2 + s][0] + wq * 64), 16, 0, 0);

  for (int p = 0; p < PAIRS; ++p) {
    // Counted own-drain THEN barrier: drains pair p (oldest, issued 2 phases
    // ago -> near-free), leaves pair p+1 in flight. Stray candi stores only
    // over-drain (in-order vmcnt) = safe. Barrier publishes pair p to all
    // waves and frees pair p-1's slots.
    if (p < PAIRS - 1) {
      asm volatile("s_waitcnt vmcnt(2)\n\ts_barrier" ::: "memory");
    } else {
      asm volatile("s_waitcnt vmcnt(0)\n\ts_barrier" ::: "memory");
    }
    __builtin_amdgcn_sched_barrier(0);
    if (p + 2 < PAIRS) {
      #pragma unroll
      for (int s = 0; s < 2; ++s) {
        int slot = ((p + 2) % 3) * 2 + s;   // == pair p-1's slots (freed)
        __builtin_amdgcn_global_load_lds(
            (g_u32*)(gbase + ((size_t)(p + 2) * 2 + s) * 512 + tid),
            (l_u32*)((uint4*)&bstage[slot][0] + wq * 64), 16, 0, 0);
      }
    }
    #pragma unroll
    for (int sl = 0; sl < 2; ++sl) {
      const unsigned char* buf = (const unsigned char*)&bstage[(p % 3) * 2 + sl][0];
      int itrow = p * 128 + sl * 64;
      #pragma unroll
      for (int half = 0; half < 2; ++half) {
        // tnh for the two tt sub-tiles of this half (one scalar per lane).
        float tnh0 = tnh_lds[itrow + half * 32 + l15];
        float tnh1 = tnh_lds[itrow + half * 32 + 16 + l15];
        f32x4 c0 = {-tnh0, -tnh0, -tnh0, -tnh0};
        f32x4 c1 = {-tnh1, -tnh1, -tnh1, -tnh1};
        short8 b[2][2];
        #pragma unroll
        for (int tt = 0; tt < 2; ++tt) {
          int nloc = half * 32 + tt * 16 + l15;
          #pragma unroll
          for (int s = 0; s < 2; ++s) {
            int c = s * 4 + quad;
            unsigned addr = (unsigned)(nloc * 128 + ((c ^ (nloc & 7)) << 4));
            b[tt][s] = *(const short8*)(buf + addr);
          }
        }
        f32x4 acc[4][2];
        #pragma unroll
        for (int mt = 0; mt < 4; ++mt)
          #pragma unroll
          for (int tt = 0; tt < 2; ++tt) {
            f32x4 a0 = __builtin_amdgcn_mfma_f32_16x16x32_bf16(
                afrag[mt][0], b[tt][0], tt ? c1 : c0, 0, 0, 0);
            acc[mt][tt] = __builtin_amdgcn_mfma_f32_16x16x32_bf16(
                afrag[mt][1], b[tt][1], a0, 0, 0, 0);
          }
        #pragma unroll
        for (int tt = 0; tt < 2; ++tt) {
          int n = rstart + itrow + half * 32 + tt * 16 + l15;
          #pragma unroll
          for (int mt = 0; mt < 4; ++mt) {
            // Exact group screen: 4 divergent bools = 4 lane-mask v_cmp in
            // SGPR pairs; bitwise-OR = s_or_b64; one execz branch. Fires iff
            // some lane has some hit (no conservatism, unlike R15).
            bool h0 = acc[mt][tt][0] > negthr[mt][0];
            bool h1 = acc[mt][tt][1] > negthr[mt][1];
            bool h2 = acc[mt][tt][2] > negthr[mt][2];
            bool h3 = acc[mt][tt][3] > negthr[mt][3];
            if (__builtin_expect((h0 | h1) | (h2 | h3), 0)) {
              #pragma unroll
              for (int r = 0; r < 4; ++r) {
                float a = acc[mt][tt][r];   // dot - tnh
                // hit <=> tnh - dot < thr <=> a > -thr.
                // padded rows: tnh=3e38 -> a hugely negative -> never fires.
                if (a > negthr[mt][r]) {
                  int ql = wq * 64 + mt * 16 + quad * 4 + r;
                  int d2q = (int)fmaf(-a, 32.f, 2048.f);
                  d2q = d2q < 0 ? 0 : (d2q > 8191 ? 8191 : d2q);
                  unsigned v = ((unsigned)d2q << 19) | (unsigned)n;
                  unsigned pp = atomicAdd(&scnt[ql], 1u);
                  if (pp < SDEPTH) {
                    sbuf[ql * SDEPTH + pp] = v;
                  } else {
                    int g = atomicAdd(&cnt[qbase + ql], 1);
                    if (g < cap) candi[(size_t)(qbase + ql) * cap + g] = v;
                  }
                }
              }
            }
          }
        }
      }
    }
  }
  __syncthreads();   // make all waves' scnt/sbuf visible for the flush
  int m = (int)scnt[tid];
  if (m > SDEPTH) m = SDEPTH;
  if (m > 0) {
    int base = atomicAdd(&cnt[qbase + tid], m);
    for (int j = 0; j < m; ++j) {
      int g = base + j;
      if (g < cap) candi[(size_t)(qbase + tid) * cap + g] = sbuf[tid * SDEPTH + j];
    }
  }
}

// ---------------- FALLBACK kernels (R9 path; only if workspace too small) ----------------
__global__ __launch_bounds__(256) void qthresh_fb(
    const float* __restrict__ keys, const float* __restrict__ tk,
    float* __restrict__ thr, float* __restrict__ qnorm, int C) {
  int q0 = blockIdx.x * FQB;
  __shared__ __align__(16) float kq[FQB * 64];
  __shared__ unsigned hist[FQB][NBINS];
  __shared__ float qn4[FQB];
  int tid = threadIdx.x;
  for (int i = tid; i < FQB * 64; i += 256) kq[i] = keys[(size_t)q0 * 64 + i];
  for (int i = tid; i < FQB * NBINS; i += 256) (&hist[0][0])[i] = 0u;
  __syncthreads();
  if (tid < FQB) {
    float s = 0.f;
    for (int j = 0; j < 64; ++j) { float v = kq[tid * 64 + j]; s += v * v; }
    qn4[tid] = s;
  }
  __syncthreads();
  int kc = tid & 3;
  const float4* kq4 = (const float4*)kq;
  float4 kf[FQB][4];
  #pragma unroll
  for (int jq = 0; jq < FQB; ++jq)
    #pragma unroll
    for (int u = 0; u < 4; ++u) kf[jq][u] = kq4[jq * 16 + kc * 4 + u];
  int S = FSAMPLE < C ? FSAMPLE : C;
  for (int r = tid >> 2; r < S; r += 64) {
    const float4* trow = (const float4*)(tk + (size_t)r * 64 + kc * 16);
    float4 t0 = trow[0], t1 = trow[1], t2 = trow[2], t3 = trow[3];
    float tn = t0.x * t0.x + t0.y * t0.y + t0.z * t0.z + t0.w * t0.w
             + t1.x * t1.x + t1.y * t1.y + t1.z * t1.z + t1.w * t1.w
             + t2.x * t2.x + t2.y * t2.y + t2.z * t2.z + t2.w * t2.w
             + t3.x * t3.x + t3.y * t3.y + t3.z * t3.z + t3.w * t3.w;
    tn += __shfl_xor(tn, 1); tn += __shfl_xor(tn, 2);
    float dot[FQB];
    #pragma unroll
    for (int jq = 0; jq < FQB; ++jq) {
      float s = kf[jq][0].x * t0.x + kf[jq][0].y * t0.y + kf[jq][0].z * t0.z + kf[jq][0].w * t0.w
              + kf[jq][1].x * t1.x + kf[jq][1].y * t1.y + kf[jq][1].z * t1.z + kf[jq][1].w * t1.w
              + kf[jq][2].x * t2.x + kf[jq][2].y * t2.y + kf[jq][2].z * t2.z + kf[jq][2].w * t2.w
              + kf[jq][3].x * t3.x + kf[jq][3].y * t3.y + kf[jq][3].z * t3.z + kf[jq][3].w * t3.w;
      s += __shfl_xor(s, 1); s += __shfl_xor(s, 2);
      dot[jq] = s;
    }
    if (kc == 0) {
      #pragma unroll
      for (int jq = 0; jq < FQB; ++jq) {
        float d2 = qn4[jq] + tn - 2.f * dot[jq];
        int b = (int)d2;
        b = b < 0 ? 0 : (b > NBINS - 1 ? NBINS - 1 : b);
        atomicAdd(&hist[jq][b], 1u);
      }
    }
  }
  __syncthreads();
  if (tid < FQB) {
    unsigned cum = 0; int bstar = NBINS - 1;
    for (int b = 0; b < NBINS; ++b) {
      cum += hist[tid][b];
      if (cum >= (unsigned)FTARGET) { bstar = b; break; }
    }
    thr[q0 + tid] = (float)(bstar + 1) + FMARGIN - qn4[tid];
    qnorm[q0 + tid] = qn4[tid];
  }
}

__global__ __launch_bounds__(512, 4) void filter_fb(
    const float* __restrict__ keys, const float* __restrict__ tk,
    const float* __restrict__ thr, const float* __restrict__ qnorm,
    int* __restrict__ cnt, unsigned* __restrict__ candi, int C, int cap) {
  __shared__ float tnstage[64];
  __shared__ float thr_lds[QTILE];
  __shared__ float qn_lds[QTILE];
  __shared__ unsigned scnt[QTILE];
  __shared__ unsigned sbuf[QTILE * SDEPTH];
  __shared__ __align__(16) unsigned char bstage[64 * 128];
  int tid = threadIdx.x;
  int qt = blockIdx.x & 1;
  int chunk = blockIdx.x >> 1;
  int qbase = qt * QTILE;
  int rstart = chunk * RPB;
  thr_lds[tid] = thr[qbase + tid];
  qn_lds[tid] = qnorm[qbase + tid];
  scnt[tid] = 0u;
  int lane = tid & 63, wq = tid >> 6, l15 = lane & 15, quad = lane >> 4;
  short8 afrag[4][2];
  #pragma unroll
  for (int mt = 0; mt < 4; ++mt) {
    const float* kp = keys + (size_t)(qbase + wq * 64 + mt * 16 + l15) * 64 + quad * 8;
    #pragma unroll
    for (int s = 0; s < 2; ++s) {
      float4 x = *(const float4*)(kp + s * 32);
      float4 y = *(const float4*)(kp + s * 32 + 4);
      short8 a;
      a[0] = (short)f2bf(x.x); a[1] = (short)f2bf(x.y);
      a[2] = (short)f2bf(x.z); a[3] = (short)f2bf(x.w);
      a[4] = (short)f2bf(y.x); a[5] = (short)f2bf(y.y);
      a[6] = (short)f2bf(y.z); a[7] = (short)f2bf(y.w);
      afrag[mt][s] = a;
    }
  }
  __syncthreads();
  float hq[4];
  #pragma unroll
  for (int mt = 0; mt < 4; ++mt) {
    float h0 = thr_lds[wq * 64 + mt * 16 + quad * 4 + 0];
    float h1 = thr_lds[wq * 64 + mt * 16 + quad * 4 + 1];
    float h2 = thr_lds[wq * 64 + mt * 16 + quad * 4 + 2];
    float h3 = thr_lds[wq * 64 + mt * 16 + quad * 4 + 3];
    hq[mt] = fmaxf(fmaxf(h0, h1), fmaxf(h2, h3));
  }
  int srow = tid >> 3, scol = tid & 7;
  unsigned sbyte = (unsigned)(srow * 128 + ((scol ^ (srow & 7)) << 4));
  const int ITERS = RPB / 64;
  int r0 = rstart + srow; if (r0 > C - 1) r0 = C - 1;
  float4 pa = *(const float4*)(tk + (size_t)r0 * 64 + scol * 8);
  float4 pb = *(const float4*)(tk + (size_t)r0 * 64 + scol * 8 + 4);
  f32x4 zero4 = {0.f, 0.f, 0.f, 0.f};
  for (int it = 0; it < ITERS; ++it) {
    float part = pa.x * pa.x + pa.y * pa.y + pa.z * pa.z + pa.w * pa.w
               + pb.x * pb.x + pb.y * pb.y + pb.z * pb.z + pb.w * pb.w;
    part += __shfl_xor(part, 1); part += __shfl_xor(part, 2); part += __shfl_xor(part, 4);
    if ((tid & 7) == 0) tnstage[srow] = part;
    uint4 u;
    u.x = f2bf(pa.x) | (f2bf(pa.y) << 16);
    u.y = f2bf(pa.z) | (f2bf(pa.w) << 16);
    u.z = f2bf(pb.x) | (f2bf(pb.y) << 16);
    u.w = f2bf(pb.z) | (f2bf(pb.w) << 16);
    *(uint4*)(bstage + sbyte) = u;
    __syncthreads();
    if (it + 1 < ITERS) {
      int rn = rstart + (it + 1) * 64 + srow; if (rn > C - 1) rn = C - 1;
      pa = *(const float4*)(tk + (size_t)rn * 64 + scol * 8);
      pb = *(const float4*)(tk + (size_t)rn * 64 + scol * 8 + 4);
    }
    #pragma unroll
    for (int half = 0; half < 2; ++half) {
      short8 b[2][2];
      #pragma unroll
      for (int tt = 0; tt < 2; ++tt) {
        int nloc = half * 32 + tt * 16 + l15;
        #pragma unroll
        for (int s = 0; s < 2; ++s) {
          int c = s * 4 + quad;
          unsigned addr = (unsigned)(nloc * 128 + ((c ^ (nloc & 7)) << 4));
          b[tt][s] = *(const short8*)(bstage + addr);
        }
      }
      f32x4 acc[4][2];
      #pragma unroll
      for (int mt = 0; mt < 4; ++mt)
        #pragma unroll
        for (int tt = 0; tt < 2; ++tt) {
          f32x4 a0 = __builtin_amdgcn_mfma_f32_16x16x32_bf16(afrag[mt][0], b[tt][0], zero4, 0, 0, 0);
          acc[mt][tt] = __builtin_amdgcn_mfma_f32_16x16x32_bf16(afrag[mt][1], b[tt][1], a0, 0, 0, 0);
        }
      #pragma unroll
      for (int tt = 0; tt < 2; ++tt) {
        float tn = tnstage[half * 32 + tt * 16 + l15];
        int n = rstart + it * 64 + half * 32 + tt * 16 + l15;
        #pragma unroll
        for (int mt = 0; mt < 4; ++mt) {
          float d0 = fmaf(-2.f, acc[mt][tt][0], tn);
          float d1 = fmaf(-2.f, acc[mt][tt][1], tn);
          float d2 = fmaf(-2.f, acc[mt][tt][2], tn);
          float d3 = fmaf(-2.f, acc[mt][tt][3], tn);
          float mn4 = fminf(fminf(d0, d1), fminf(d2, d3));
          if (mn4 < hq[mt]) {
            float dd[4] = {d0, d1, d2, d3};
            #pragma unroll
            for (int r = 0; r < 4; ++r) {
              int ql = wq * 64 + mt * 16 + quad * 4 + r;
              if (dd[r] < thr_lds[ql] && n < C) {
                float d2f = dd[r] + qn_lds[ql];
                int d2q = (int)(d2f * 16.f);
                d2q = d2q < 0 ? 0 : (d2q > 8191 ? 8191 : d2q);
                unsigned v = ((unsigned)d2q << 19) | (unsigned)n;
                unsigned p = atomicAdd(&scnt[ql], 1u);
                if (p < SDEPTH) sbuf[ql * SDEPTH + p] = v;
                else {
                  int g = atomicAdd(&cnt[qbase + ql], 1);
                  if (g < cap) candi[(size_t)(qbase + ql) * cap + g] = v;
                }
              }
            }
          }
        }
      }
    }
    __syncthreads();
  }
  int m = (int)scnt[tid];
  if (m > SDEPTH) m = SDEPTH;
  if (m > 0) {
    int base = atomicAdd(&cnt[qbase + tid], m);
    for (int j = 0; j < m; ++j) {
      int g = base + j;
      if (g < cap) candi[(size_t)(qbase + tid) * cap + g] = sbuf[tid * SDEPTH + j];
    }
  }
}

// ---------------- Kernel 3: select (payload-order agnostic; fp32 rescore) ----------------
__global__ __launch_bounds__(256) void select_kernel(
    const float* __restrict__ keys, const float* __restrict__ tk,
    const float* __restrict__ tv, const int* __restrict__ cnt,
    const unsigned* __restrict__ candi, float* __restrict__ out, int cap) {
  int q = blockIdx.x;
  __shared__ unsigned cvl[CVL];
  __shared__ unsigned hist[NBINS];
  __shared__ unsigned wsum[4];
  __shared__ unsigned minq_sh;
  __shared__ int b50_sh;
  __shared__ int lidx[LW];
  __shared__ unsigned ed2[LW];
  __shared__ int m_sh;
  __shared__ float redw[4], redwv[4];
  int tid = threadIdx.x;
  int lane = tid & 63;
  int wid = tid >> 6;
  int n = cnt[q];
  if (n > cap) n = cap;
  hist[tid] = 0u;
  if (tid == 0) { minq_sh = 0xffffffffu; b50_sh = NBINS - 1; m_sh = 0; }
  __syncthreads();
  const unsigned* cv = candi + (size_t)q * cap;
  unsigned mn = 0xffffffffu;
  for (int i = tid; i < n; i += 256) {
    unsigned v = cv[i];
    if (i < CVL) cvl[i] = v;
    unsigned d = v >> 19; if (d < mn) mn = d;
  }
  #pragma unroll
  for (int off = 1; off < 64; off <<= 1) { unsigned o = __shfl_xor(mn, off); if (o < mn) mn = o; }
  if (lane == 0) atomicMin(&minq_sh, mn);
  __syncthreads();
  unsigned base = minq_sh;
  for (int i = tid; i < n; i += 256) {
    unsigned v = (i < CVL) ? cvl[i] : cv[i];
    unsigned d = (v >> 19) - base;
    unsigned b = d >> 1; if (b > NBINS - 1) b = NBINS - 1;
    atomicAdd(&hist[b], 1u);
  }
  __syncthreads();
  unsigned h = hist[tid];
  unsigned p = h;
  #pragma unroll
  for (int off = 1; off < 64; off <<= 1) {
    unsigned v = __shfl_up(p, off);
    if (lane >= off) p += v;
  }
  if (lane == 63) wsum[wid] = p;
  __syncthreads();
  unsigned add = 0;
  for (int w2 = 0; w2 < wid; ++w2) add += wsum[w2];
  p += add;
  if (p >= (unsigned)K_NEIGH && p - h < (unsigned)K_NEIGH) b50_sh = tid;
  __syncthreads();
  unsigned Tq = base + (((unsigned)(b50_sh + 1)) << 1) + MARGIN_Q;
  for (int i = tid; i < n; i += 256) {
    unsigned v = (i < CVL) ? cvl[i] : cv[i];
    if ((v >> 19) <= Tq) {
      int p2 = atomicAdd(&m_sh, 1);
      if (p2 < LW) lidx[p2] = (int)(v & 0x7ffffu);
    }
  }
  __syncthreads();
  int m = m_sh; if (m > LW) m = LW;
  float kqv = keys[(size_t)q * 64 + lane];
  for (int i0 = wid * 4; i0 < m; i0 += 16) {
    int mm = m - i0; if (mm > 4) mm = 4;
    int idx[4]; float t[4];
    for (int u = 0; u < mm; ++u) idx[u] = lidx[i0 + u];
    for (int u = 0; u < mm; ++u) t[u] = tk[(size_t)idx[u] * 64 + lane];
    for (int u = 0; u < mm; ++u) {
      float d = t[u] - kqv;
      float s = d * d;
      #pragma unroll
      for (int off = 1; off < 64; off <<= 1) s += __shfl_xor(s, off);
      if (lane == 0) ed2[i0 + u] = __float_as_uint(s);
    }
  }
  __syncthreads();
  float accw = 0.f, accwv = 0.f;
  for (int i = tid; i < m; i += 256) {
    unsigned long long key = ((unsigned long long)ed2[i] << 19) | (unsigned)lidx[i];
    int rank = 0;
    for (int j = 0; j < m; ++j) {
      unsigned long long kj = ((unsigned long long)ed2[j] << 19) | (unsigned)lidx[j];
      rank += (kj < key) ? 1 : 0;
    }
    if (rank < K_NEIGH) {
      float d2 = __uint_as_float(ed2[i]);
      float w = 1.f / (d2 + DELTA_SMOOTH);
      accw += w;
      accwv += w * tv[lidx[i]];
    }
  }
  #pragma unroll
  for (int off = 1; off < 64; off <<= 1) {
    accw += __shfl_xor(accw, off);
    accwv += __shfl_xor(accwv, off);
  }
  if (lane == 0) { redw[wid] = accw; redwv[wid] = accwv; }
  __syncthreads();
  if (tid == 0) {
    float sw = redw[0] + redw[1] + redw[2] + redw[3];
    float swv = redwv[0] + redwv[1] + redwv[2] + redwv[3];
    out[q] = swv / sw;
  }
}

extern "C" void kernel_launch(void* const* d_in, const int* in_sizes, int n_in,
                              void* d_out, int out_size, void* d_ws, size_t ws_size,
                              hipStream_t stream) {
  const float* keys = (const float*)d_in[0];   // [B,64]
  const float* tk   = (const float*)d_in[1];   // [C,64]
  const float* tv   = (const float*)d_in[2];   // [C]
  float* out = (float*)d_out;
  int B = in_sizes[0] / 64;   // 1024
  int C = in_sizes[2];        // 500000 (< 2^19 for packing)

  int nchunks = (C + RPB - 1) / RPB;
  int padded = nchunks * RPB;

  char* w = (char*)d_ws;
  float* thrh = (float*)w;  w += (size_t)B * 4;   // fast: thr/2 | fb: thr
  float* qnfb = (float*)w;  w += (size_t)B * 4;   // fallback qn
  int*   cnt  = (int*)w;    w += (size_t)B * 4;
  size_t fixed = (size_t)(w - (char*)d_ws);

  size_t tk_bytes = (size_t)padded * 128 + (size_t)padded * 4;
  size_t dsamp_bytes = (size_t)S_SAMP * (size_t)B * 2;   // 16.8 MB
  size_t region = ws_size > fixed + tk_bytes ? ws_size - fixed - tk_bytes : 0;
  bool fast = region >= dsamp_bytes && region >= 2048ull * (size_t)B * 4;

  if (fast) {
    uint4* tkbf = (uint4*)w;              w += (size_t)padded * 128;
    float* tnh2 = (float*)w;              w += (size_t)padded * 4;
    // dsamp and candi alias the same region (sequential lifetimes)
    unsigned short* dsamp = (unsigned short*)w;
    unsigned* candi = (unsigned*)w;
    int cap = (int)(region / (4ull * (size_t)B));
    if (cap > MAXCAP) cap = MAXCAP;
    convert_kernel<<<(padded * 8 + 255) / 256, 256, 0, stream>>>(tk, tkbf, tnh2, C, padded);
    qthresh_mfma<<<(S_SAMP / 64) * 2, 512, 0, stream>>>(tkbf, keys, tnh2, dsamp);
    qthresh_scan<<<B, 256, 0, stream>>>(dsamp, thrh, cnt);   // also zeros cnt
    filter_mfma_fast<<<nchunks * 2, 512, 0, stream>>>(tkbf, keys, tnh2, thrh,
                                                      cnt, candi, C, cap);
    select_kernel<<<B, 256, 0, stream>>>(keys, tk, tv, cnt, candi, out, cap);
  } else {
    unsigned* candi = (unsigned*)w;
    int cap = (int)((ws_size - fixed) / (4ull * (size_t)B));
    if (cap > MAXCAP) cap = MAXCAP;
    if (cap < 1) cap = 1;
    hipMemsetAsync(cnt, 0, (size_t)B * 4, stream);
    qthresh_fb<<<B / FQB, 256, 0, stream>>>(keys, tk, thrh, qnfb, C);
    filter_fb<<<nchunks * 2, 512, 0, stream>>>(keys, tk, thrh, qnfb,
                                               cnt, candi, C, cap);
    select_kernel<<<B, 256, 0, stream>>>(keys, tk, tv, cnt, candi, out, cap);
  }
}

// Round 11
// 380.502 us; speedup vs baseline: 1.0888x; 1.0888x over previous
//
#include <hip/hip_runtime.h>
#include <math.h>

// kNN (B=1024, C=500000, D=64) + inverse-distance weighting, top-50.
// R19: REVERT R18's exact-OR screen (filter 131->172us: branch-fabric
// restructure worsened codegen + desynced paired blocks -> FETCH +17MB,
// WRITE +30MB). Third failed screen attempt -> lever closed: flat per-value
// cmpx/cbranch predication (R17) is optimal for rare hits. KEEP R18's
// qthresh_mfma regrid (256 blocks of one 64-row tile; rest 247->242us).
// Filter = R17 exactly: 3-pair ring, depth-2 prefetch, counted vmcnt(2)
// own-drain BEFORE s_barrier (race-free), C-seeded MFMA (acc = dot - tnh),
// reg-resident negated thresholds, flat per-value hit test.

#define DELTA_SMOOTH 1e-3f
#define K_NEIGH 50
#define MAXCAP 8192
#define NBINS 256
#define MARGIN_T 1.5f      // bf16 dot error margin, both directions (d2 units)
#define MARGIN_Q 26        // select margin in d2q quanta (16 per d2 unit)
#define RPB 1024           // table rows per filter block
#define QTILE 512          // queries per filter block (8 waves x 64)
#define SDEPTH 6           // LDS staging slots per (block,query)
#define LW 768             // select rescore list size
#define CVL 2048           // select LDS candidate cache
#define S_SAMP 8192        // qthresh sample rows
#define T_SAMP 8           // order statistic -> E[count] ~ 488
// fallback (R5/R9-style) constants
#define FSAMPLE 2048
#define FTARGET 6
#define FMARGIN 0.75f
#define FQB 4

typedef __attribute__((ext_vector_type(8))) short short8;
typedef __attribute__((ext_vector_type(4))) float f32x4;
typedef __attribute__((address_space(1))) const unsigned int g_u32;
typedef __attribute__((address_space(3))) unsigned int l_u32;

__device__ __forceinline__ unsigned f2bf(float f) {
  unsigned u = __float_as_uint(f);
  return ((u + 0x7fffu + ((u >> 16) & 1u)) >> 16) & 0xffffu;
}

// ---------------- Kernel 0: table -> bf16 swizzled 64-row tiles + halved norms ----------------
// Row r chunk c (8 bf16 = 16 B) at uint4 index (r>>6)*512 + (r&63)*8 + (c^(r&7)).
// Padded rows (r >= C) get tnh2 = 3e38 so the filter predicate never fires.
__global__ __launch_bounds__(256) void convert_kernel(
    const float* __restrict__ tk, uint4* __restrict__ tkbf,
    float* __restrict__ tnh2, int C, int padded) {
  int t = blockIdx.x * 256 + threadIdx.x;
  int r = t >> 3;
  if (r >= padded) return;
  int c = t & 7;
  int rs = r < C ? r : C - 1;
  const float4* src = (const float4*)(tk + (size_t)rs * 64 + c * 8);
  float4 a = src[0], b = src[1];
  float sq = a.x * a.x + a.y * a.y + a.z * a.z + a.w * a.w
           + b.x * b.x + b.y * b.y + b.z * b.z + b.w * b.w;
  sq += __shfl_xor(sq, 1); sq += __shfl_xor(sq, 2); sq += __shfl_xor(sq, 4);
  if (c == 0) tnh2[r] = (r < C) ? sq * 0.5f : 3e38f;
  uint4 u;
  u.x = f2bf(a.x) | (f2bf(a.y) << 16);
  u.y = f2bf(a.z) | (f2bf(a.w) << 16);
  u.z = f2bf(b.x) | (f2bf(b.y) << 16);
  u.w = f2bf(b.z) | (f2bf(b.w) << 16);
  tkbf[(size_t)(r >> 6) * 512 + (r & 63) * 8 + (c ^ (r & 7))] = u;
}

// ---------------- Kernel 1a: sampled bf16 d2' via MFMA -> u16 store ----------------
// (S_SAMP/64)*2 = 256 blocks: (64-row chunk) x (2 query tiles) -> full machine.
// d2' = 2*(tnh - dot); u16 = clamp((d2' + 128) * 256).
__global__ __launch_bounds__(512, 4) void qthresh_mfma(
    const uint4* __restrict__ tkbf, const float* __restrict__ keys,
    const float* __restrict__ tnh2, unsigned short* __restrict__ dsamp) {
  __shared__ __align__(16) uint4 bstage[512];   // one 64-row tile (8 KB)
  __shared__ float tnh_lds[64];
  int tid = threadIdx.x;
  int qt = blockIdx.x & 1;
  int chunk = blockIdx.x >> 1;       // 0..S_SAMP/64-1
  int qbase = qt * 512;
  int rstart = chunk * 64;
  if (tid < 64) tnh_lds[tid] = tnh2[rstart + tid];
  int lane = tid & 63, wq = tid >> 6, l15 = lane & 15, quad = lane >> 4;
  short8 afrag[4][2];
  #pragma unroll
  for (int mt = 0; mt < 4; ++mt) {
    const float* kp = keys + (size_t)(qbase + wq * 64 + mt * 16 + l15) * 64 + quad * 8;
    #pragma unroll
    for (int s = 0; s < 2; ++s) {
      float4 x = *(const float4*)(kp + s * 32);
      float4 y = *(const float4*)(kp + s * 32 + 4);
      short8 a;
      a[0] = (short)f2bf(x.x); a[1] = (short)f2bf(x.y);
      a[2] = (short)f2bf(x.z); a[3] = (short)f2bf(x.w);
      a[4] = (short)f2bf(y.x); a[5] = (short)f2bf(y.y);
      a[6] = (short)f2bf(y.z); a[7] = (short)f2bf(y.w);
      afrag[mt][s] = a;
    }
  }
  const uint4* gbase = tkbf + (size_t)chunk * 512;
  __builtin_amdgcn_global_load_lds((g_u32*)(gbase + tid),
                                   (l_u32*)((uint4*)&bstage[0] + wq * 64), 16, 0, 0);
  __syncthreads();
  f32x4 zero4 = {0.f, 0.f, 0.f, 0.f};
  const unsigned char* buf = (const unsigned char*)bstage;
  #pragma unroll
  for (int half = 0; half < 2; ++half) {
    short8 b[2][2];
    #pragma unroll
    for (int tt = 0; tt < 2; ++tt) {
      int nloc = half * 32 + tt * 16 + l15;
      #pragma unroll
      for (int s = 0; s < 2; ++s) {
        int c = s * 4 + quad;
        unsigned addr = (unsigned)(nloc * 128 + ((c ^ (nloc & 7)) << 4));
        b[tt][s] = *(const short8*)(buf + addr);
      }
    }
    f32x4 acc[4][2];
    #pragma unroll
    for (int mt = 0; mt < 4; ++mt)
      #pragma unroll
      for (int tt = 0; tt < 2; ++tt) {
        f32x4 a0 = __builtin_amdgcn_mfma_f32_16x16x32_bf16(afrag[mt][0], b[tt][0], zero4, 0, 0, 0);
        acc[mt][tt] = __builtin_amdgcn_mfma_f32_16x16x32_bf16(afrag[mt][1], b[tt][1], a0, 0, 0, 0);
      }
    #pragma unroll
    for (int tt = 0; tt < 2; ++tt) {
      int rloc = half * 32 + tt * 16 + l15;
      float tnh = tnh_lds[rloc];
      int n = rstart + rloc;
      #pragma unroll
      for (int mt = 0; mt < 4; ++mt) {
        #pragma unroll
        for (int r = 0; r < 4; ++r) {
          int ql = wq * 64 + mt * 16 + quad * 4 + r;
          // u16 = (2*(tnh-acc) + 128)*256 = (tnh-acc)*512 + 32768
          int u = (int)fmaf(tnh - acc[mt][tt][r], 512.f, 32768.f);
          u = u < 0 ? 0 : (u > 65535 ? 65535 : u);
          dsamp[(size_t)(qbase + ql) * S_SAMP + n] = (unsigned short)u;
        }
      }
    }
  }
}

// ---------------- Kernel 1b: per-query T-th smallest -> halved threshold ----------------
__global__ __launch_bounds__(256) void qthresh_scan(
    const unsigned short* __restrict__ dsamp, float* __restrict__ thrh,
    int* __restrict__ cnt) {
  int q = blockIdx.x;
  __shared__ unsigned hist[512];
  int tid = threadIdx.x;
  hist[tid] = 0u; hist[tid + 256] = 0u;
  __syncthreads();
  const unsigned short* dp = dsamp + (size_t)q * S_SAMP;
  for (int i = tid; i < S_SAMP; i += 256) atomicAdd(&hist[dp[i] >> 7], 1u);
  __syncthreads();
  if (tid == 0) {
    unsigned cum = 0; int bstar = 511;
    for (int b = 0; b < 512; ++b) {
      cum += hist[b];
      if (cum >= (unsigned)T_SAMP) { bstar = b; break; }
    }
    // bin width 0.5 in d2' space; thr = binUpper + margin; store thr/2
    float thr = (float)(bstar + 1) * 0.5f - 128.f + MARGIN_T;
    thrh[q] = 0.5f * thr;
    cnt[q] = 0;
  }
}

// ---------------- Kernel 2a: 512-thr filter, 3-pair ring, counted-wait publication ----------------
// 8 waves / 512 queries per block, 2 blocks per 1024-row chunk. Pair p's DMA
// issued during phase p-2 (depth 2); at phase p: s_waitcnt vmcnt(2) drains
// pair p (leaves p+1 in flight) THEN s_barrier publishes it -> race-free with
// a near-free wait. Pair p+2 -> slots of pair p-1 (freed by this barrier).
// MFMA C seeded with -tnh -> acc = dot - tnh; hit <=> acc > -thr (1 cmp,
// flat per-value predication -- R15/R18 screens both regressed).
__global__ __launch_bounds__(512, 4) void filter_mfma_fast(
    const uint4* __restrict__ tkbf, const float* __restrict__ keys,
    const float* __restrict__ tnh2, const float* __restrict__ thrh,
    int* __restrict__ cnt, unsigned* __restrict__ candi, int C, int cap) {
  __shared__ __align__(16) uint4 bstage[6][512];          // 48 KB: 3 pairs
  __shared__ float tnh_lds[RPB];                          // 4 KB
  __shared__ float thr_lds[QTILE];                        // 2 KB (halved thr)
  __shared__ unsigned scnt[QTILE];                        // 2 KB
  __shared__ unsigned sbuf[QTILE * SDEPTH];               // 12 KB  (total 68 KB)

  int tid = threadIdx.x;
  int qt = blockIdx.x & 1;
  int chunk = blockIdx.x >> 1;
  int qbase = qt * QTILE;
  int rstart = chunk * RPB;

  tnh_lds[tid] = tnh2[rstart + tid];
  tnh_lds[tid + 512] = tnh2[rstart + tid + 512];
  thr_lds[tid] = thrh[qbase + tid];
  scnt[tid] = 0u;

  int lane = tid & 63, wq = tid >> 6, l15 = lane & 15, quad = lane >> 4;

  short8 afrag[4][2];
  #pragma unroll
  for (int mt = 0; mt < 4; ++mt) {
    const float* kp = keys + (size_t)(qbase + wq * 64 + mt * 16 + l15) * 64 + quad * 8;
    #pragma unroll
    for (int s = 0; s < 2; ++s) {
      float4 x = *(const float4*)(kp + s * 32);
      float4 y = *(const float4*)(kp + s * 32 + 4);
      short8 a;
      a[0] = (short)f2bf(x.x); a[1] = (short)f2bf(x.y);
      a[2] = (short)f2bf(x.z); a[3] = (short)f2bf(x.w);
      a[4] = (short)f2bf(y.x); a[5] = (short)f2bf(y.y);
      a[6] = (short)f2bf(y.z); a[7] = (short)f2bf(y.w);
      afrag[mt][s] = a;
    }
  }

  // Drains all prior vector loads (vmcnt ledger clean) + publishes thr_lds.
  __syncthreads();

  // Negated thresholds for this thread's 16 (mt, r) queries -> registers.
  float negthr[4][4];
  #pragma unroll
  for (int mt = 0; mt < 4; ++mt)
    #pragma unroll
    for (int r = 0; r < 4; ++r)
      negthr[mt][r] = -thr_lds[wq * 64 + mt * 16 + quad * 4 + r];

  const uint4* gbase = tkbf + (size_t)(rstart >> 6) * 512;
  const int PAIRS = RPB / 128;   // 8
  // prologue: pairs 0 and 1 in flight (depth 2; pair j -> slots (j%3)*2, +1)
  #pragma unroll
  for (int s = 0; s < 2; ++s)
    __builtin_amdgcn_global_load_lds((g_u32*)(gbase + (size_t)s * 512 + tid),
                                     (l_u32*)((uint4*)&bstage[s][0] + wq * 64), 16, 0, 0);
  #pragma unroll
  for (int s = 0; s < 2; ++s)
    __builtin_amdgcn_global_load_lds((g_u32*)(gbase + (size_t)(2 + s) * 512 + tid),
                                     (l_u32*)((uint4*)&bstage[2 + s][0] + wq * 64), 16, 0, 0);

  for (int p = 0; p < PAIRS; ++p) {
    // Counted own-drain THEN barrier: drains pair p (oldest, issued 2 phases
    // ago -> near-free), leaves pair p+1 in flight. Stray candi stores only
    // over-drain (in-order vmcnt) = safe. Barrier publishes pair p to all
    // waves and frees pair p-1's slots.
    if (p < PAIRS - 1) {
      asm volatile("s_waitcnt vmcnt(2)\n\ts_barrier" ::: "memory");
    } else {
      asm volatile("s_waitcnt vmcnt(0)\n\ts_barrier" ::: "memory");
    }
    __builtin_amdgcn_sched_barrier(0);
    if (p + 2 < PAIRS) {
      #pragma unroll
      for (int s = 0; s < 2; ++s) {
        int slot = ((p + 2) % 3) * 2 + s;   // == pair p-1's slots (freed)
        __builtin_amdgcn_global_load_lds(
            (g_u32*)(gbase + ((size_t)(p + 2) * 2 + s) * 512 + tid),
            (l_u32*)((uint4*)&bstage[slot][0] + wq * 64), 16, 0, 0);
      }
    }
    #pragma unroll
    for (int sl = 0; sl < 2; ++sl) {
      const unsigned char* buf = (const unsigned char*)&bstage[(p % 3) * 2 + sl][0];
      int itrow = p * 128 + sl * 64;
      #pragma unroll
      for (int half = 0; half < 2; ++half) {
        // tnh for the two tt sub-tiles of this half (one scalar per lane).
        float tnh0 = tnh_lds[itrow + half * 32 + l15];
        float tnh1 = tnh_lds[itrow + half * 32 + 16 + l15];
        f32x4 c0 = {-tnh0, -tnh0, -tnh0, -tnh0};
        f32x4 c1 = {-tnh1, -tnh1, -tnh1, -tnh1};
        short8 b[2][2];
        #pragma unroll
        for (int tt = 0; tt < 2; ++tt) {
          int nloc = half * 32 + tt * 16 + l15;
          #pragma unroll
          for (int s = 0; s < 2; ++s) {
            int c = s * 4 + quad;
            unsigned addr = (unsigned)(nloc * 128 + ((c ^ (nloc & 7)) << 4));
            b[tt][s] = *(const short8*)(buf + addr);
          }
        }
        f32x4 acc[4][2];
        #pragma unroll
        for (int mt = 0; mt < 4; ++mt)
          #pragma unroll
          for (int tt = 0; tt < 2; ++tt) {
            f32x4 a0 = __builtin_amdgcn_mfma_f32_16x16x32_bf16(
                afrag[mt][0], b[tt][0], tt ? c1 : c0, 0, 0, 0);
            acc[mt][tt] = __builtin_amdgcn_mfma_f32_16x16x32_bf16(
                afrag[mt][1], b[tt][1], a0, 0, 0, 0);
          }
        #pragma unroll
        for (int tt = 0; tt < 2; ++tt) {
          int n = rstart + itrow + half * 32 + tt * 16 + l15;
          #pragma unroll
          for (int mt = 0; mt < 4; ++mt) {
            #pragma unroll
            for (int r = 0; r < 4; ++r) {
              float a = acc[mt][tt][r];   // dot - tnh
              // hit <=> tnh - dot < thr <=> a > -thr.
              // padded rows: tnh=3e38 -> a hugely negative -> never fires.
              if (__builtin_expect(a > negthr[mt][r], 0)) {
                int ql = wq * 64 + mt * 16 + quad * 4 + r;
                int d2q = (int)fmaf(-a, 32.f, 2048.f);
                d2q = d2q < 0 ? 0 : (d2q > 8191 ? 8191 : d2q);
                unsigned v = ((unsigned)d2q << 19) | (unsigned)n;
                unsigned pp = atomicAdd(&scnt[ql], 1u);
                if (pp < SDEPTH) {
                  sbuf[ql * SDEPTH + pp] = v;
                } else {
                  int g = atomicAdd(&cnt[qbase + ql], 1);
                  if (g < cap) candi[(size_t)(qbase + ql) * cap + g] = v;
                }
              }
            }
          }
        }
      }
    }
  }
  __syncthreads();   // make all waves' scnt/sbuf visible for the flush
  int m = (int)scnt[tid];
  if (m > SDEPTH) m = SDEPTH;
  if (m > 0) {
    int base = atomicAdd(&cnt[qbase + tid], m);
    for (int j = 0; j < m; ++j) {
      int g = base + j;
      if (g < cap) candi[(size_t)(qbase + tid) * cap + g] = sbuf[tid * SDEPTH + j];
    }
  }
}

// ---------------- FALLBACK kernels (R9 path; only if workspace too small) ----------------
__global__ __launch_bounds__(256) void qthresh_fb(
    const float* __restrict__ keys, const float* __restrict__ tk,
    float* __restrict__ thr, float* __restrict__ qnorm, int C) {
  int q0 = blockIdx.x * FQB;
  __shared__ __align__(16) float kq[FQB * 64];
  __shared__ unsigned hist[FQB][NBINS];
  __shared__ float qn4[FQB];
  int tid = threadIdx.x;
  for (int i = tid; i < FQB * 64; i += 256) kq[i] = keys[(size_t)q0 * 64 + i];
  for (int i = tid; i < FQB * NBINS; i += 256) (&hist[0][0])[i] = 0u;
  __syncthreads();
  if (tid < FQB) {
    float s = 0.f;
    for (int j = 0; j < 64; ++j) { float v = kq[tid * 64 + j]; s += v * v; }
    qn4[tid] = s;
  }
  __syncthreads();
  int kc = tid & 3;
  const float4* kq4 = (const float4*)kq;
  float4 kf[FQB][4];
  #pragma unroll
  for (int jq = 0; jq < FQB; ++jq)
    #pragma unroll
    for (int u = 0; u < 4; ++u) kf[jq][u] = kq4[jq * 16 + kc * 4 + u];
  int S = FSAMPLE < C ? FSAMPLE : C;
  for (int r = tid >> 2; r < S; r += 64) {
    const float4* trow = (const float4*)(tk + (size_t)r * 64 + kc * 16);
    float4 t0 = trow[0], t1 = trow[1], t2 = trow[2], t3 = trow[3];
    float tn = t0.x * t0.x + t0.y * t0.y + t0.z * t0.z + t0.w * t0.w
             + t1.x * t1.x + t1.y * t1.y + t1.z * t1.z + t1.w * t1.w
             + t2.x * t2.x + t2.y * t2.y + t2.z * t2.z + t2.w * t2.w
             + t3.x * t3.x + t3.y * t3.y + t3.z * t3.z + t3.w * t3.w;
    tn += __shfl_xor(tn, 1); tn += __shfl_xor(tn, 2);
    float dot[FQB];
    #pragma unroll
    for (int jq = 0; jq < FQB; ++jq) {
      float s = kf[jq][0].x * t0.x + kf[jq][0].y * t0.y + kf[jq][0].z * t0.z + kf[jq][0].w * t0.w
              + kf[jq][1].x * t1.x + kf[jq][1].y * t1.y + kf[jq][1].z * t1.z + kf[jq][1].w * t1.w
              + kf[jq][2].x * t2.x + kf[jq][2].y * t2.y + kf[jq][2].z * t2.z + kf[jq][2].w * t2.w
              + kf[jq][3].x * t3.x + kf[jq][3].y * t3.y + kf[jq][3].z * t3.z + kf[jq][3].w * t3.w;
      s += __shfl_xor(s, 1); s += __shfl_xor(s, 2);
      dot[jq] = s;
    }
    if (kc == 0) {
      #pragma unroll
      for (int jq = 0; jq < FQB; ++jq) {
        float d2 = qn4[jq] + tn - 2.f * dot[jq];
        int b = (int)d2;
        b = b < 0 ? 0 : (b > NBINS - 1 ? NBINS - 1 : b);
        atomicAdd(&hist[jq][b], 1u);
      }
    }
  }
  __syncthreads();
  if (tid < FQB) {
    unsigned cum = 0; int bstar = NBINS - 1;
    for (int b = 0; b < NBINS; ++b) {
      cum += hist[tid][b];
      if (cum >= (unsigned)FTARGET) { bstar = b; break; }
    }
    thr[q0 + tid] = (float)(bstar + 1) + FMARGIN - qn4[tid];
    qnorm[q0 + tid] = qn4[tid];
  }
}

__global__ __launch_bounds__(512, 4) void filter_fb(
    const float* __restrict__ keys, const float* __restrict__ tk,
    const float* __restrict__ thr, const float* __restrict__ qnorm,
    int* __restrict__ cnt, unsigned* __restrict__ candi, int C, int cap) {
  __shared__ float tnstage[64];
  __shared__ float thr_lds[QTILE];
  __shared__ float qn_lds[QTILE];
  __shared__ unsigned scnt[QTILE];
  __shared__ unsigned sbuf[QTILE * SDEPTH];
  __shared__ __align__(16) unsigned char bstage[64 * 128];
  int tid = threadIdx.x;
  int qt = blockIdx.x & 1;
  int chunk = blockIdx.x >> 1;
  int qbase = qt * QTILE;
  int rstart = chunk * RPB;
  thr_lds[tid] = thr[qbase + tid];
  qn_lds[tid] = qnorm[qbase + tid];
  scnt[tid] = 0u;
  int lane = tid & 63, wq = tid >> 6, l15 = lane & 15, quad = lane >> 4;
  short8 afrag[4][2];
  #pragma unroll
  for (int mt = 0; mt < 4; ++mt) {
    const float* kp = keys + (size_t)(qbase + wq * 64 + mt * 16 + l15) * 64 + quad * 8;
    #pragma unroll
    for (int s = 0; s < 2; ++s) {
      float4 x = *(const float4*)(kp + s * 32);
      float4 y = *(const float4*)(kp + s * 32 + 4);
      short8 a;
      a[0] = (short)f2bf(x.x); a[1] = (short)f2bf(x.y);
      a[2] = (short)f2bf(x.z); a[3] = (short)f2bf(x.w);
      a[4] = (short)f2bf(y.x); a[5] = (short)f2bf(y.y);
      a[6] = (short)f2bf(y.z); a[7] = (short)f2bf(y.w);
      afrag[mt][s] = a;
    }
  }
  __syncthreads();
  float hq[4];
  #pragma unroll
  for (int mt = 0; mt < 4; ++mt) {
    float h0 = thr_lds[wq * 64 + mt * 16 + quad * 4 + 0];
    float h1 = thr_lds[wq * 64 + mt * 16 + quad * 4 + 1];
    float h2 = thr_lds[wq * 64 + mt * 16 + quad * 4 + 2];
    float h3 = thr_lds[wq * 64 + mt * 16 + quad * 4 + 3];
    hq[mt] = fmaxf(fmaxf(h0, h1), fmaxf(h2, h3));
  }
  int srow = tid >> 3, scol = tid & 7;
  unsigned sbyte = (unsigned)(srow * 128 + ((scol ^ (srow & 7)) << 4));
  const int ITERS = RPB / 64;
  int r0 = rstart + srow; if (r0 > C - 1) r0 = C - 1;
  float4 pa = *(const float4*)(tk + (size_t)r0 * 64 + scol * 8);
  float4 pb = *(const float4*)(tk + (size_t)r0 * 64 + scol * 8 + 4);
  f32x4 zero4 = {0.f, 0.f, 0.f, 0.f};
  for (int it = 0; it < ITERS; ++it) {
    float part = pa.x * pa.x + pa.y * pa.y + pa.z * pa.z + pa.w * pa.w
               + pb.x * pb.x + pb.y * pb.y + pb.z * pb.z + pb.w * pb.w;
    part += __shfl_xor(part, 1); part += __shfl_xor(part, 2); part += __shfl_xor(part, 4);
    if ((tid & 7) == 0) tnstage[srow] = part;
    uint4 u;
    u.x = f2bf(pa.x) | (f2bf(pa.y) << 16);
    u.y = f2bf(pa.z) | (f2bf(pa.w) << 16);
    u.z = f2bf(pb.x) | (f2bf(pb.y) << 16);
    u.w = f2bf(pb.z) | (f2bf(pb.w) << 16);
    *(uint4*)(bstage + sbyte) = u;
    __syncthreads();
    if (it + 1 < ITERS) {
      int rn = rstart + (it + 1) * 64 + srow; if (rn > C - 1) rn = C - 1;
      pa = *(const float4*)(tk + (size_t)rn * 64 + scol * 8);
      pb = *(const float4*)(tk + (size_t)rn * 64 + scol * 8 + 4);
    }
    #pragma unroll
    for (int half = 0; half < 2; ++half) {
      short8 b[2][2];
      #pragma unroll
      for (int tt = 0; tt < 2; ++tt) {
        int nloc = half * 32 + tt * 16 + l15;
        #pragma unroll
        for (int s = 0; s < 2; ++s) {
          int c = s * 4 + quad;
          unsigned addr = (unsigned)(nloc * 128 + ((c ^ (nloc & 7)) << 4));
          b[tt][s] = *(const short8*)(bstage + addr);
        }
      }
      f32x4 acc[4][2];
      #pragma unroll
      for (int mt = 0; mt < 4; ++mt)
        #pragma unroll
        for (int tt = 0; tt < 2; ++tt) {
          f32x4 a0 = __builtin_amdgcn_mfma_f32_16x16x32_bf16(afrag[mt][0], b[tt][0], zero4, 0, 0, 0);
          acc[mt][tt] = __builtin_amdgcn_mfma_f32_16x16x32_bf16(afrag[mt][1], b[tt][1], a0, 0, 0, 0);
        }
      #pragma unroll
      for (int tt = 0; tt < 2; ++tt) {
        float tn = tnstage[half * 32 + tt * 16 + l15];
        int n = rstart + it * 64 + half * 32 + tt * 16 + l15;
        #pragma unroll
        for (int mt = 0; mt < 4; ++mt) {
          float d0 = fmaf(-2.f, acc[mt][tt][0], tn);
          float d1 = fmaf(-2.f, acc[mt][tt][1], tn);
          float d2 = fmaf(-2.f, acc[mt][tt][2], tn);
          float d3 = fmaf(-2.f, acc[mt][tt][3], tn);
          float mn4 = fminf(fminf(d0, d1), fminf(d2, d3));
          if (mn4 < hq[mt]) {
            float dd[4] = {d0, d1, d2, d3};
            #pragma unroll
            for (int r = 0; r < 4; ++r) {
              int ql = wq * 64 + mt * 16 + quad * 4 + r;
              if (dd[r] < thr_lds[ql] && n < C) {
                float d2f = dd[r] + qn_lds[ql];
                int d2q = (int)(d2f * 16.f);
                d2q = d2q < 0 ? 0 : (d2q > 8191 ? 8191 : d2q);
                unsigned v = ((unsigned)d2q << 19) | (unsigned)n;
                unsigned p = atomicAdd(&scnt[ql], 1u);
                if (p < SDEPTH) sbuf[ql * SDEPTH + p] = v;
                else {
                  int g = atomicAdd(&cnt[qbase + ql], 1);
                  if (g < cap) candi[(size_t)(qbase + ql) * cap + g] = v;
                }
              }
            }
          }
        }
      }
    }
    __syncthreads();
  }
  int m = (int)scnt[tid];
  if (m > SDEPTH) m = SDEPTH;
  if (m > 0) {
    int base = atomicAdd(&cnt[qbase + tid], m);
    for (int j = 0; j < m; ++j) {
      int g = base + j;
      if (g < cap) candi[(size_t)(qbase + tid) * cap + g] = sbuf[tid * SDEPTH + j];
    }
  }
}

// ---------------- Kernel 3: select (payload-order agnostic; fp32 rescore) ----------------
__global__ __launch_bounds__(256) void select_kernel(
    const float* __restrict__ keys, const float* __restrict__ tk,
    const float* __restrict__ tv, const int* __restrict__ cnt,
    const unsigned* __restrict__ candi, float* __restrict__ out, int cap) {
  int q = blockIdx.x;
  __shared__ unsigned cvl[CVL];
  __shared__ unsigned hist[NBINS];
  __shared__ unsigned wsum[4];
  __shared__ unsigned minq_sh;
  __shared__ int b50_sh;
  __shared__ int lidx[LW];
  __shared__ unsigned ed2[LW];
  __shared__ int m_sh;
  __shared__ float redw[4], redwv[4];
  int tid = threadIdx.x;
  int lane = tid & 63;
  int wid = tid >> 6;
  int n = cnt[q];
  if (n > cap) n = cap;
  hist[tid] = 0u;
  if (tid == 0) { minq_sh = 0xffffffffu; b50_sh = NBINS - 1; m_sh = 0; }
  __syncthreads();
  const unsigned* cv = candi + (size_t)q * cap;
  unsigned mn = 0xffffffffu;
  for (int i = tid; i < n; i += 256) {
    unsigned v = cv[i];
    if (i < CVL) cvl[i] = v;
    unsigned d = v >> 19; if (d < mn) mn = d;
  }
  #pragma unroll
  for (int off = 1; off < 64; off <<= 1) { unsigned o = __shfl_xor(mn, off); if (o < mn) mn = o; }
  if (lane == 0) atomicMin(&minq_sh, mn);
  __syncthreads();
  unsigned base = minq_sh;
  for (int i = tid; i < n; i += 256) {
    unsigned v = (i < CVL) ? cvl[i] : cv[i];
    unsigned d = (v >> 19) - base;
    unsigned b = d >> 1; if (b > NBINS - 1) b = NBINS - 1;
    atomicAdd(&hist[b], 1u);
  }
  __syncthreads();
  unsigned h = hist[tid];
  unsigned p = h;
  #pragma unroll
  for (int off = 1; off < 64; off <<= 1) {
    unsigned v = __shfl_up(p, off);
    if (lane >= off) p += v;
  }
  if (lane == 63) wsum[wid] = p;
  __syncthreads();
  unsigned add = 0;
  for (int w2 = 0; w2 < wid; ++w2) add += wsum[w2];
  p += add;
  if (p >= (unsigned)K_NEIGH && p - h < (unsigned)K_NEIGH) b50_sh = tid;
  __syncthreads();
  unsigned Tq = base + (((unsigned)(b50_sh + 1)) << 1) + MARGIN_Q;
  for (int i = tid; i < n; i += 256) {
    unsigned v = (i < CVL) ? cvl[i] : cv[i];
    if ((v >> 19) <= Tq) {
      int p2 = atomicAdd(&m_sh, 1);
      if (p2 < LW) lidx[p2] = (int)(v & 0x7ffffu);
    }
  }
  __syncthreads();
  int m = m_sh; if (m > LW) m = LW;
  float kqv = keys[(size_t)q * 64 + lane];
  for (int i0 = wid * 4; i0 < m; i0 += 16) {
    int mm = m - i0; if (mm > 4) mm = 4;
    int idx[4]; float t[4];
    for (int u = 0; u < mm; ++u) idx[u] = lidx[i0 + u];
    for (int u = 0; u < mm; ++u) t[u] = tk[(size_t)idx[u] * 64 + lane];
    for (int u = 0; u < mm; ++u) {
      float d = t[u] - kqv;
      float s = d * d;
      #pragma unroll
      for (int off = 1; off < 64; off <<= 1) s += __shfl_xor(s, off);
      if (lane == 0) ed2[i0 + u] = __float_as_uint(s);
    }
  }
  __syncthreads();
  float accw = 0.f, accwv = 0.f;
  for (int i = tid; i < m; i += 256) {
    unsigned long long key = ((unsigned long long)ed2[i] << 19) | (unsigned)lidx[i];
    int rank = 0;
    for (int j = 0; j < m; ++j) {
      unsigned long long kj = ((unsigned long long)ed2[j] << 19) | (unsigned)lidx[j];
      rank += (kj < key) ? 1 : 0;
    }
    if (rank < K_NEIGH) {
      float d2 = __uint_as_float(ed2[i]);
      float w = 1.f / (d2 + DELTA_SMOOTH);
      accw += w;
      accwv += w * tv[lidx[i]];
    }
  }
  #pragma unroll
  for (int off = 1; off < 64; off <<= 1) {
    accw += __shfl_xor(accw, off);
    accwv += __shfl_xor(accwv, off);
  }
  if (lane == 0) { redw[wid] = accw; redwv[wid] = accwv; }
  __syncthreads();
  if (tid == 0) {
    float sw = redw[0] + redw[1] + redw[2] + redw[3];
    float swv = redwv[0] + redwv[1] + redwv[2] + redwv[3];
    out[q] = swv / sw;
  }
}

extern "C" void kernel_launch(void* const* d_in, const int* in_sizes, int n_in,
                              void* d_out, int out_size, void* d_ws, size_t ws_size,
                              hipStream_t stream) {
  const float* keys = (const float*)d_in[0];   // [B,64]
  const float* tk   = (const float*)d_in[1];   // [C,64]
  const float* tv   = (const float*)d_in[2];   // [C]
  float* out = (float*)d_out;
  int B = in_sizes[0] / 64;   // 1024
  int C = in_sizes[2];        // 500000 (< 2^19 for packing)

  int nchunks = (C + RPB - 1) / RPB;
  int padded = nchunks * RPB;

  char* w = (char*)d_ws;
  float* thrh = (float*)w;  w += (size_t)B * 4;   // fast: thr/2 | fb: thr
  float* qnfb = (float*)w;  w += (size_t)B * 4;   // fallback qn
  int*   cnt  = (int*)w;    w += (size_t)B * 4;
  size_t fixed = (size_t)(w - (char*)d_ws);

  size_t tk_bytes = (size_t)padded * 128 + (size_t)padded * 4;
  size_t dsamp_bytes = (size_t)S_SAMP * (size_t)B * 2;   // 16.8 MB
  size_t region = ws_size > fixed + tk_bytes ? ws_size - fixed - tk_bytes : 0;
  bool fast = region >= dsamp_bytes && region >= 2048ull * (size_t)B * 4;

  if (fast) {
    uint4* tkbf = (uint4*)w;              w += (size_t)padded * 128;
    float* tnh2 = (float*)w;              w += (size_t)padded * 4;
    // dsamp and candi alias the same region (sequential lifetimes)
    unsigned short* dsamp = (unsigned short*)w;
    unsigned* candi = (unsigned*)w;
    int cap = (int)(region / (4ull * (size_t)B));
    if (cap > MAXCAP) cap = MAXCAP;
    convert_kernel<<<(padded * 8 + 255) / 256, 256, 0, stream>>>(tk, tkbf, tnh2, C, padded);
    qthresh_mfma<<<(S_SAMP / 64) * 2, 512, 0, stream>>>(tkbf, keys, tnh2, dsamp);
    qthresh_scan<<<B, 256, 0, stream>>>(dsamp, thrh, cnt);   // also zeros cnt
    filter_mfma_fast<<<nchunks * 2, 512, 0, stream>>>(tkbf, keys, tnh2, thrh,
                                                      cnt, candi, C, cap);
    select_kernel<<<B, 256, 0, stream>>>(keys, tk, tv, cnt, candi, out, cap);
  } else {
    unsigned* candi = (unsigned*)w;
    int cap = (int)((ws_size - fixed) / (4ull * (size_t)B));
    if (cap > MAXCAP) cap = MAXCAP;
    if (cap < 1) cap = 1;
    hipMemsetAsync(cnt, 0, (size_t)B * 4, stream);
    qthresh_fb<<<B / FQB, 256, 0, stream>>>(keys, tk, thrh, qnfb, C);
    filter_fb<<<nchunks * 2, 512, 0, stream>>>(keys, tk, thrh, qnfb,
                                               cnt, candi, C, cap);
    select_kernel<<<B, 256, 0, stream>>>(keys, tk, tv, cnt, candi, out, cap);
  }
}

// Round 12
// 371.685 us; speedup vs baseline: 1.1146x; 1.0237x over previous
//
#include <hip/hip_runtime.h>
#include <math.h>

// kNN (B=1024, C=500000, D=64) + inverse-distance weighting, top-50.
// R20: kernel-count experiment. "Rest" (total - filter) has been 247+-5us
// across ALL configs since R12, insensitive to qthresh size (S_SAMP halving
// moved it ~7us) -> bottom-up component sum is only ~80us -> theory: ~25-30us
// fixed cost per kernel boundary (launch + device drain + tail). Test by
// removing one boundary: convert and qthresh sampling are INDEPENDENT if the
// sampler converts its 8192 rows inline (fb-style staging + inline norms).
// Jammed into one kernel, role-split by blockIdx. 5 kernels -> 4.
// Filter = R17/R19 exactly (133us verified floor). Decision rule: total
// ~350-358 => overhead confirmed, keep fusing; ~375-385 => theory dead.

#define DELTA_SMOOTH 1e-3f
#define K_NEIGH 50
#define MAXCAP 8192
#define NBINS 256
#define MARGIN_T 1.5f      // bf16 dot error margin, both directions (d2 units)
#define MARGIN_Q 26        // select margin in d2q quanta (16 per d2 unit)
#define RPB 1024           // table rows per filter block
#define QTILE 512          // queries per filter block (8 waves x 64)
#define SDEPTH 6           // LDS staging slots per (block,query)
#define LW 768             // select rescore list size
#define CVL 2048           // select LDS candidate cache
#define S_SAMP 8192        // qthresh sample rows
#define T_SAMP 8           // order statistic -> E[count] ~ 488
// fallback (R5/R9-style) constants
#define FSAMPLE 2048
#define FTARGET 6
#define FMARGIN 0.75f
#define FQB 4

typedef __attribute__((ext_vector_type(8))) short short8;
typedef __attribute__((ext_vector_type(4))) float f32x4;
typedef __attribute__((address_space(1))) const unsigned int g_u32;
typedef __attribute__((address_space(3))) unsigned int l_u32;

__device__ __forceinline__ unsigned f2bf(float f) {
  unsigned u = __float_as_uint(f);
  return ((u + 0x7fffu + ((u >> 16) & 1u)) >> 16) & 0xffffu;
}

// ---------------- Kernel 1 (fused): table convert + sampled d2' via MFMA ----------------
// Role split by blockIdx:
//  blocks [0, convB):     table -> bf16 swizzled 64-row tiles + halved norms.
//    Row r chunk c (8 bf16 = 16 B) at uint4 idx (r>>6)*512 + (r&63)*8 + (c^(r&7)).
//    Padded rows (r >= C) get tnh2 = 3e38 (filter predicate never fires).
//  blocks [convB, convB+256): qthresh sampling, INDEPENDENT of convert role:
//    stages its 64 sample rows from tk fp32 inline (fb-style swizzled LDS
//    write + inline halved norms), then MFMA d2' -> u16 dsamp store.
//    d2' = 2*(tnh - dot); u16 = clamp((d2' + 128) * 256).
__global__ __launch_bounds__(512, 4) void convert_qthresh(
    const float* __restrict__ tk, uint4* __restrict__ tkbf,
    float* __restrict__ tnh2, const float* __restrict__ keys,
    unsigned short* __restrict__ dsamp, int C, int padded, int convB) {
  __shared__ __align__(16) unsigned char bstage[64 * 128];   // 8 KB tile
  __shared__ float tnh_lds[64];
  int tid = threadIdx.x;

  if (blockIdx.x < (unsigned)convB) {
    // ---- convert role (memory-bound; 64 rows per 512-thread block) ----
    int t = blockIdx.x * 512 + tid;
    int r = t >> 3;
    if (r >= padded) return;
    int c = t & 7;
    int rs = r < C ? r : C - 1;
    const float4* src = (const float4*)(tk + (size_t)rs * 64 + c * 8);
    float4 a = src[0], b = src[1];
    float sq = a.x * a.x + a.y * a.y + a.z * a.z + a.w * a.w
             + b.x * b.x + b.y * b.y + b.z * b.z + b.w * b.w;
    sq += __shfl_xor(sq, 1); sq += __shfl_xor(sq, 2); sq += __shfl_xor(sq, 4);
    if (c == 0) tnh2[r] = (r < C) ? sq * 0.5f : 3e38f;
    uint4 u;
    u.x = f2bf(a.x) | (f2bf(a.y) << 16);
    u.y = f2bf(a.z) | (f2bf(a.w) << 16);
    u.z = f2bf(b.x) | (f2bf(b.y) << 16);
    u.w = f2bf(b.z) | (f2bf(b.w) << 16);
    tkbf[(size_t)(r >> 6) * 512 + (r & 63) * 8 + (c ^ (r & 7))] = u;
    return;
  }

  // ---- qthresh sampling role (no dependency on convert output) ----
  int bid = blockIdx.x - convB;
  int qt = bid & 1;
  int chunk = bid >> 1;              // 0..S_SAMP/64-1
  int qbase = qt * 512;
  int rstart = chunk * 64;           // S_SAMP <= C: no clamp needed
  int lane = tid & 63, wq = tid >> 6, l15 = lane & 15, quad = lane >> 4;

  // Inline stage: 512 threads cover 64 rows x 8 chunks; swizzled layout
  // identical to tkbf tiles so the b-frag read formula below matches.
  int srow = tid >> 3, scol = tid & 7;
  const float* rowp = tk + (size_t)(rstart + srow) * 64 + scol * 8;
  float4 pa = *(const float4*)(rowp);
  float4 pb = *(const float4*)(rowp + 4);
  float part = pa.x * pa.x + pa.y * pa.y + pa.z * pa.z + pa.w * pa.w
             + pb.x * pb.x + pb.y * pb.y + pb.z * pb.z + pb.w * pb.w;
  part += __shfl_xor(part, 1); part += __shfl_xor(part, 2); part += __shfl_xor(part, 4);
  if (scol == 0) tnh_lds[srow] = part * 0.5f;
  uint4 u;
  u.x = f2bf(pa.x) | (f2bf(pa.y) << 16);
  u.y = f2bf(pa.z) | (f2bf(pa.w) << 16);
  u.z = f2bf(pb.x) | (f2bf(pb.y) << 16);
  u.w = f2bf(pb.z) | (f2bf(pb.w) << 16);
  *(uint4*)(bstage + (unsigned)(srow * 128 + ((scol ^ (srow & 7)) << 4))) = u;

  short8 afrag[4][2];
  #pragma unroll
  for (int mt = 0; mt < 4; ++mt) {
    const float* kp = keys + (size_t)(qbase + wq * 64 + mt * 16 + l15) * 64 + quad * 8;
    #pragma unroll
    for (int s = 0; s < 2; ++s) {
      float4 x = *(const float4*)(kp + s * 32);
      float4 y = *(const float4*)(kp + s * 32 + 4);
      short8 a;
      a[0] = (short)f2bf(x.x); a[1] = (short)f2bf(x.y);
      a[2] = (short)f2bf(x.z); a[3] = (short)f2bf(x.w);
      a[4] = (short)f2bf(y.x); a[5] = (short)f2bf(y.y);
      a[6] = (short)f2bf(y.z); a[7] = (short)f2bf(y.w);
      afrag[mt][s] = a;
    }
  }
  __syncthreads();
  f32x4 zero4 = {0.f, 0.f, 0.f, 0.f};
  #pragma unroll
  for (int half = 0; half < 2; ++half) {
    short8 b[2][2];
    #pragma unroll
    for (int tt = 0; tt < 2; ++tt) {
      int nloc = half * 32 + tt * 16 + l15;
      #pragma unroll
      for (int s = 0; s < 2; ++s) {
        int c = s * 4 + quad;
        unsigned addr = (unsigned)(nloc * 128 + ((c ^ (nloc & 7)) << 4));
        b[tt][s] = *(const short8*)(bstage + addr);
      }
    }
    f32x4 acc[4][2];
    #pragma unroll
    for (int mt = 0; mt < 4; ++mt)
      #pragma unroll
      for (int tt = 0; tt < 2; ++tt) {
        f32x4 a0 = __builtin_amdgcn_mfma_f32_16x16x32_bf16(afrag[mt][0], b[tt][0], zero4, 0, 0, 0);
        acc[mt][tt] = __builtin_amdgcn_mfma_f32_16x16x32_bf16(afrag[mt][1], b[tt][1], a0, 0, 0, 0);
      }
    #pragma unroll
    for (int tt = 0; tt < 2; ++tt) {
      int rloc = half * 32 + tt * 16 + l15;
      float tnh = tnh_lds[rloc];
      int n = rstart + rloc;
      #pragma unroll
      for (int mt = 0; mt < 4; ++mt) {
        #pragma unroll
        for (int r = 0; r < 4; ++r) {
          int ql = wq * 64 + mt * 16 + quad * 4 + r;
          // u16 = (2*(tnh-acc) + 128)*256 = (tnh-acc)*512 + 32768
          int uq = (int)fmaf(tnh - acc[mt][tt][r], 512.f, 32768.f);
          uq = uq < 0 ? 0 : (uq > 65535 ? 65535 : uq);
          dsamp[(size_t)(qbase + ql) * S_SAMP + n] = (unsigned short)uq;
        }
      }
    }
  }
}

// ---------------- Kernel 1b: per-query T-th smallest -> halved threshold ----------------
__global__ __launch_bounds__(256) void qthresh_scan(
    const unsigned short* __restrict__ dsamp, float* __restrict__ thrh,
    int* __restrict__ cnt) {
  int q = blockIdx.x;
  __shared__ unsigned hist[512];
  int tid = threadIdx.x;
  hist[tid] = 0u; hist[tid + 256] = 0u;
  __syncthreads();
  const unsigned short* dp = dsamp + (size_t)q * S_SAMP;
  for (int i = tid; i < S_SAMP; i += 256) atomicAdd(&hist[dp[i] >> 7], 1u);
  __syncthreads();
  if (tid == 0) {
    unsigned cum = 0; int bstar = 511;
    for (int b = 0; b < 512; ++b) {
      cum += hist[b];
      if (cum >= (unsigned)T_SAMP) { bstar = b; break; }
    }
    // bin width 0.5 in d2' space; thr = binUpper + margin; store thr/2
    float thr = (float)(bstar + 1) * 0.5f - 128.f + MARGIN_T;
    thrh[q] = 0.5f * thr;
    cnt[q] = 0;
  }
}

// ---------------- Kernel 2a: 512-thr filter, 3-pair ring, counted-wait publication ----------------
// 8 waves / 512 queries per block, 2 blocks per 1024-row chunk. Pair p's DMA
// issued during phase p-2 (depth 2); at phase p: s_waitcnt vmcnt(2) drains
// pair p (leaves p+1 in flight) THEN s_barrier publishes it -> race-free with
// a near-free wait. Pair p+2 -> slots of pair p-1 (freed by this barrier).
// MFMA C seeded with -tnh -> acc = dot - tnh; hit <=> acc > -thr (1 cmp,
// flat per-value predication -- R15/R18 screens both regressed).
__global__ __launch_bounds__(512, 4) void filter_mfma_fast(
    const uint4* __restrict__ tkbf, const float* __restrict__ keys,
    const float* __restrict__ tnh2, const float* __restrict__ thrh,
    int* __restrict__ cnt, unsigned* __restrict__ candi, int C, int cap) {
  __shared__ __align__(16) uint4 bstage[6][512];          // 48 KB: 3 pairs
  __shared__ float tnh_lds[RPB];                          // 4 KB
  __shared__ float thr_lds[QTILE];                        // 2 KB (halved thr)
  __shared__ unsigned scnt[QTILE];                        // 2 KB
  __shared__ unsigned sbuf[QTILE * SDEPTH];               // 12 KB  (total 68 KB)

  int tid = threadIdx.x;
  int qt = blockIdx.x & 1;
  int chunk = blockIdx.x >> 1;
  int qbase = qt * QTILE;
  int rstart = chunk * RPB;

  tnh_lds[tid] = tnh2[rstart + tid];
  tnh_lds[tid + 512] = tnh2[rstart + tid + 512];
  thr_lds[tid] = thrh[qbase + tid];
  scnt[tid] = 0u;

  int lane = tid & 63, wq = tid >> 6, l15 = lane & 15, quad = lane >> 4;

  short8 afrag[4][2];
  #pragma unroll
  for (int mt = 0; mt < 4; ++mt) {
    const float* kp = keys + (size_t)(qbase + wq * 64 + mt * 16 + l15) * 64 + quad * 8;
    #pragma unroll
    for (int s = 0; s < 2; ++s) {
      float4 x = *(const float4*)(kp + s * 32);
      float4 y = *(const float4*)(kp + s * 32 + 4);
      short8 a;
      a[0] = (short)f2bf(x.x); a[1] = (short)f2bf(x.y);
      a[2] = (short)f2bf(x.z); a[3] = (short)f2bf(x.w);
      a[4] = (short)f2bf(y.x); a[5] = (short)f2bf(y.y);
      a[6] = (short)f2bf(y.z); a[7] = (short)f2bf(y.w);
      afrag[mt][s] = a;
    }
  }

  // Drains all prior vector loads (vmcnt ledger clean) + publishes thr_lds.
  __syncthreads();

  // Negated thresholds for this thread's 16 (mt, r) queries -> registers.
  float negthr[4][4];
  #pragma unroll
  for (int mt = 0; mt < 4; ++mt)
    #pragma unroll
    for (int r = 0; r < 4; ++r)
      negthr[mt][r] = -thr_lds[wq * 64 + mt * 16 + quad * 4 + r];

  const uint4* gbase = tkbf + (size_t)(rstart >> 6) * 512;
  const int PAIRS = RPB / 128;   // 8
  // prologue: pairs 0 and 1 in flight (depth 2; pair j -> slots (j%3)*2, +1)
  #pragma unroll
  for (int s = 0; s < 2; ++s)
    __builtin_amdgcn_global_load_lds((g_u32*)(gbase + (size_t)s * 512 + tid),
                                     (l_u32*)((uint4*)&bstage[s][0] + wq * 64), 16, 0, 0);
  #pragma unroll
  for (int s = 0; s < 2; ++s)
    __builtin_amdgcn_global_load_lds((g_u32*)(gbase + (size_t)(2 + s) * 512 + tid),
                                     (l_u32*)((uint4*)&bstage[2 + s][0] + wq * 64), 16, 0, 0);

  for (int p = 0; p < PAIRS; ++p) {
    // Counted own-drain THEN barrier: drains pair p (oldest, issued 2 phases
    // ago -> near-free), leaves pair p+1 in flight. Stray candi stores only
    // over-drain (in-order vmcnt) = safe. Barrier publishes pair p to all
    // waves and frees pair p-1's slots.
    if (p < PAIRS - 1) {
      asm volatile("s_waitcnt vmcnt(2)\n\ts_barrier" ::: "memory");
    } else {
      asm volatile("s_waitcnt vmcnt(0)\n\ts_barrier" ::: "memory");
    }
    __builtin_amdgcn_sched_barrier(0);
    if (p + 2 < PAIRS) {
      #pragma unroll
      for (int s = 0; s < 2; ++s) {
        int slot = ((p + 2) % 3) * 2 + s;   // == pair p-1's slots (freed)
        __builtin_amdgcn_global_load_lds(
            (g_u32*)(gbase + ((size_t)(p + 2) * 2 + s) * 512 + tid),
            (l_u32*)((uint4*)&bstage[slot][0] + wq * 64), 16, 0, 0);
      }
    }
    #pragma unroll
    for (int sl = 0; sl < 2; ++sl) {
      const unsigned char* buf = (const unsigned char*)&bstage[(p % 3) * 2 + sl][0];
      int itrow = p * 128 + sl * 64;
      #pragma unroll
      for (int half = 0; half < 2; ++half) {
        // tnh for the two tt sub-tiles of this half (one scalar per lane).
        float tnh0 = tnh_lds[itrow + half * 32 + l15];
        float tnh1 = tnh_lds[itrow + half * 32 + 16 + l15];
        f32x4 c0 = {-tnh0, -tnh0, -tnh0, -tnh0};
        f32x4 c1 = {-tnh1, -tnh1, -tnh1, -tnh1};
        short8 b[2][2];
        #pragma unroll
        for (int tt = 0; tt < 2; ++tt) {
          int nloc = half * 32 + tt * 16 + l15;
          #pragma unroll
          for (int s = 0; s < 2; ++s) {
            int c = s * 4 + quad;
            unsigned addr = (unsigned)(nloc * 128 + ((c ^ (nloc & 7)) << 4));
            b[tt][s] = *(const short8*)(buf + addr);
          }
        }
        f32x4 acc[4][2];
        #pragma unroll
        for (int mt = 0; mt < 4; ++mt)
          #pragma unroll
          for (int tt = 0; tt < 2; ++tt) {
            f32x4 a0 = __builtin_amdgcn_mfma_f32_16x16x32_bf16(
                afrag[mt][0], b[tt][0], tt ? c1 : c0, 0, 0, 0);
            acc[mt][tt] = __builtin_amdgcn_mfma_f32_16x16x32_bf16(
                afrag[mt][1], b[tt][1], a0, 0, 0, 0);
          }
        #pragma unroll
        for (int tt = 0; tt < 2; ++tt) {
          int n = rstart + itrow + half * 32 + tt * 16 + l15;
          #pragma unroll
          for (int mt = 0; mt < 4; ++mt) {
            #pragma unroll
            for (int r = 0; r < 4; ++r) {
              float a = acc[mt][tt][r];   // dot - tnh
              // hit <=> tnh - dot < thr <=> a > -thr.
              // padded rows: tnh=3e38 -> a hugely negative -> never fires.
              if (__builtin_expect(a > negthr[mt][r], 0)) {
                int ql = wq * 64 + mt * 16 + quad * 4 + r;
                int d2q = (int)fmaf(-a, 32.f, 2048.f);
                d2q = d2q < 0 ? 0 : (d2q > 8191 ? 8191 : d2q);
                unsigned v = ((unsigned)d2q << 19) | (unsigned)n;
                unsigned pp = atomicAdd(&scnt[ql], 1u);
                if (pp < SDEPTH) {
                  sbuf[ql * SDEPTH + pp] = v;
                } else {
                  int g = atomicAdd(&cnt[qbase + ql], 1);
                  if (g < cap) candi[(size_t)(qbase + ql) * cap + g] = v;
                }
              }
            }
          }
        }
      }
    }
  }
  __syncthreads();   // make all waves' scnt/sbuf visible for the flush
  int m = (int)scnt[tid];
  if (m > SDEPTH) m = SDEPTH;
  if (m > 0) {
    int base = atomicAdd(&cnt[qbase + tid], m);
    for (int j = 0; j < m; ++j) {
      int g = base + j;
      if (g < cap) candi[(size_t)(qbase + tid) * cap + g] = sbuf[tid * SDEPTH + j];
    }
  }
}

// ---------------- FALLBACK kernels (R9 path; only if workspace too small) ----------------
__global__ __launch_bounds__(256) void qthresh_fb(
    const float* __restrict__ keys, const float* __restrict__ tk,
    float* __restrict__ thr, float* __restrict__ qnorm, int C) {
  int q0 = blockIdx.x * FQB;
  __shared__ __align__(16) float kq[FQB * 64];
  __shared__ unsigned hist[FQB][NBINS];
  __shared__ float qn4[FQB];
  int tid = threadIdx.x;
  for (int i = tid; i < FQB * 64; i += 256) kq[i] = keys[(size_t)q0 * 64 + i];
  for (int i = tid; i < FQB * NBINS; i += 256) (&hist[0][0])[i] = 0u;
  __syncthreads();
  if (tid < FQB) {
    float s = 0.f;
    for (int j = 0; j < 64; ++j) { float v = kq[tid * 64 + j]; s += v * v; }
    qn4[tid] = s;
  }
  __syncthreads();
  int kc = tid & 3;
  const float4* kq4 = (const float4*)kq;
  float4 kf[FQB][4];
  #pragma unroll
  for (int jq = 0; jq < FQB; ++jq)
    #pragma unroll
    for (int u = 0; u < 4; ++u) kf[jq][u] = kq4[jq * 16 + kc * 4 + u];
  int S = FSAMPLE < C ? FSAMPLE : C;
  for (int r = tid >> 2; r < S; r += 64) {
    const float4* trow = (const float4*)(tk + (size_t)r * 64 + kc * 16);
    float4 t0 = trow[0], t1 = trow[1], t2 = trow[2], t3 = trow[3];
    float tn = t0.x * t0.x + t0.y * t0.y + t0.z * t0.z + t0.w * t0.w
             + t1.x * t1.x + t1.y * t1.y + t1.z * t1.z + t1.w * t1.w
             + t2.x * t2.x + t2.y * t2.y + t2.z * t2.z + t2.w * t2.w
             + t3.x * t3.x + t3.y * t3.y + t3.z * t3.z + t3.w * t3.w;
    tn += __shfl_xor(tn, 1); tn += __shfl_xor(tn, 2);
    float dot[FQB];
    #pragma unroll
    for (int jq = 0; jq < FQB; ++jq) {
      float s = kf[jq][0].x * t0.x + kf[jq][0].y * t0.y + kf[jq][0].z * t0.z + kf[jq][0].w * t0.w
              + kf[jq][1].x * t1.x + kf[jq][1].y * t1.y + kf[jq][1].z * t1.z + kf[jq][1].w * t1.w
              + kf[jq][2].x * t2.x + kf[jq][2].y * t2.y + kf[jq][2].z * t2.z + kf[jq][2].w * t2.w
              + kf[jq][3].x * t3.x + kf[jq][3].y * t3.y + kf[jq][3].z * t3.z + kf[jq][3].w * t3.w;
      s += __shfl_xor(s, 1); s += __shfl_xor(s, 2);
      dot[jq] = s;
    }
    if (kc == 0) {
      #pragma unroll
      for (int jq = 0; jq < FQB; ++jq) {
        float d2 = qn4[jq] + tn - 2.f * dot[jq];
        int b = (int)d2;
        b = b < 0 ? 0 : (b > NBINS - 1 ? NBINS - 1 : b);
        atomicAdd(&hist[jq][b], 1u);
      }
    }
  }
  __syncthreads();
  if (tid < FQB) {
    unsigned cum = 0; int bstar = NBINS - 1;
    for (int b = 0; b < NBINS; ++b) {
      cum += hist[tid][b];
      if (cum >= (unsigned)FTARGET) { bstar = b; break; }
    }
    thr[q0 + tid] = (float)(bstar + 1) + FMARGIN - qn4[tid];
    qnorm[q0 + tid] = qn4[tid];
  }
}

__global__ __launch_bounds__(512, 4) void filter_fb(
    const float* __restrict__ keys, const float* __restrict__ tk,
    const float* __restrict__ thr, const float* __restrict__ qnorm,
    int* __restrict__ cnt, unsigned* __restrict__ candi, int C, int cap) {
  __shared__ float tnstage[64];
  __shared__ float thr_lds[QTILE];
  __shared__ float qn_lds[QTILE];
  __shared__ unsigned scnt[QTILE];
  __shared__ unsigned sbuf[QTILE * SDEPTH];
  __shared__ __align__(16) unsigned char bstage[64 * 128];
  int tid = threadIdx.x;
  int qt = blockIdx.x & 1;
  int chunk = blockIdx.x >> 1;
  int qbase = qt * QTILE;
  int rstart = chunk * RPB;
  thr_lds[tid] = thr[qbase + tid];
  qn_lds[tid] = qnorm[qbase + tid];
  scnt[tid] = 0u;
  int lane = tid & 63, wq = tid >> 6, l15 = lane & 15, quad = lane >> 4;
  short8 afrag[4][2];
  #pragma unroll
  for (int mt = 0; mt < 4; ++mt) {
    const float* kp = keys + (size_t)(qbase + wq * 64 + mt * 16 + l15) * 64 + quad * 8;
    #pragma unroll
    for (int s = 0; s < 2; ++s) {
      float4 x = *(const float4*)(kp + s * 32);
      float4 y = *(const float4*)(kp + s * 32 + 4);
      short8 a;
      a[0] = (short)f2bf(x.x); a[1] = (short)f2bf(x.y);
      a[2] = (short)f2bf(x.z); a[3] = (short)f2bf(x.w);
      a[4] = (short)f2bf(y.x); a[5] = (short)f2bf(y.y);
      a[6] = (short)f2bf(y.z); a[7] = (short)f2bf(y.w);
      afrag[mt][s] = a;
    }
  }
  __syncthreads();
  float hq[4];
  #pragma unroll
  for (int mt = 0; mt < 4; ++mt) {
    float h0 = thr_lds[wq * 64 + mt * 16 + quad * 4 + 0];
    float h1 = thr_lds[wq * 64 + mt * 16 + quad * 4 + 1];
    float h2 = thr_lds[wq * 64 + mt * 16 + quad * 4 + 2];
    float h3 = thr_lds[wq * 64 + mt * 16 + quad * 4 + 3];
    hq[mt] = fmaxf(fmaxf(h0, h1), fmaxf(h2, h3));
  }
  int srow = tid >> 3, scol = tid & 7;
  unsigned sbyte = (unsigned)(srow * 128 + ((scol ^ (srow & 7)) << 4));
  const int ITERS = RPB / 64;
  int r0 = rstart + srow; if (r0 > C - 1) r0 = C - 1;
  float4 pa = *(const float4*)(tk + (size_t)r0 * 64 + scol * 8);
  float4 pb = *(const float4*)(tk + (size_t)r0 * 64 + scol * 8 + 4);
  f32x4 zero4 = {0.f, 0.f, 0.f, 0.f};
  for (int it = 0; it < ITERS; ++it) {
    float part = pa.x * pa.x + pa.y * pa.y + pa.z * pa.z + pa.w * pa.w
               + pb.x * pb.x + pb.y * pb.y + pb.z * pb.z + pb.w * pb.w;
    part += __shfl_xor(part, 1); part += __shfl_xor(part, 2); part += __shfl_xor(part, 4);
    if ((tid & 7) == 0) tnstage[srow] = part;
    uint4 u;
    u.x = f2bf(pa.x) | (f2bf(pa.y) << 16);
    u.y = f2bf(pa.z) | (f2bf(pa.w) << 16);
    u.z = f2bf(pb.x) | (f2bf(pb.y) << 16);
    u.w = f2bf(pb.z) | (f2bf(pb.w) << 16);
    *(uint4*)(bstage + sbyte) = u;
    __syncthreads();
    if (it + 1 < ITERS) {
      int rn = rstart + (it + 1) * 64 + srow; if (rn > C - 1) rn = C - 1;
      pa = *(const float4*)(tk + (size_t)rn * 64 + scol * 8);
      pb = *(const float4*)(tk + (size_t)rn * 64 + scol * 8 + 4);
    }
    #pragma unroll
    for (int half = 0; half < 2; ++half) {
      short8 b[2][2];
      #pragma unroll
      for (int tt = 0; tt < 2; ++tt) {
        int nloc = half * 32 + tt * 16 + l15;
        #pragma unroll
        for (int s = 0; s < 2; ++s) {
          int c = s * 4 + quad;
          unsigned addr = (unsigned)(nloc * 128 + ((c ^ (nloc & 7)) << 4));
          b[tt][s] = *(const short8*)(bstage + addr);
        }
      }
      f32x4 acc[4][2];
      #pragma unroll
      for (int mt = 0; mt < 4; ++mt)
        #pragma unroll
        for (int tt = 0; tt < 2; ++tt) {
          f32x4 a0 = __builtin_amdgcn_mfma_f32_16x16x32_bf16(afrag[mt][0], b[tt][0], zero4, 0, 0, 0);
          acc[mt][tt] = __builtin_amdgcn_mfma_f32_16x16x32_bf16(afrag[mt][1], b[tt][1], a0, 0, 0, 0);
        }
      #pragma unroll
      for (int tt = 0; tt < 2; ++tt) {
        float tn = tnstage[half * 32 + tt * 16 + l15];
        int n = rstart + it * 64 + half * 32 + tt * 16 + l15;
        #pragma unroll
        for (int mt = 0; mt < 4; ++mt) {
          float d0 = fmaf(-2.f, acc[mt][tt][0], tn);
          float d1 = fmaf(-2.f, acc[mt][tt][1], tn);
          float d2 = fmaf(-2.f, acc[mt][tt][2], tn);
          float d3 = fmaf(-2.f, acc[mt][tt][3], tn);
          float mn4 = fminf(fminf(d0, d1), fminf(d2, d3));
          if (mn4 < hq[mt]) {
            float dd[4] = {d0, d1, d2, d3};
            #pragma unroll
            for (int r = 0; r < 4; ++r) {
              int ql = wq * 64 + mt * 16 + quad * 4 + r;
              if (dd[r] < thr_lds[ql] && n < C) {
                float d2f = dd[r] + qn_lds[ql];
                int d2q = (int)(d2f * 16.f);
                d2q = d2q < 0 ? 0 : (d2q > 8191 ? 8191 : d2q);
                unsigned v = ((unsigned)d2q << 19) | (unsigned)n;
                unsigned p = atomicAdd(&scnt[ql], 1u);
                if (p < SDEPTH) sbuf[ql * SDEPTH + p] = v;
                else {
                  int g = atomicAdd(&cnt[qbase + ql], 1);
                  if (g < cap) candi[(size_t)(qbase + ql) * cap + g] = v;
                }
              }
            }
          }
        }
      }
    }
    __syncthreads();
  }
  int m = (int)scnt[tid];
  if (m > SDEPTH) m = SDEPTH;
  if (m > 0) {
    int base = atomicAdd(&cnt[qbase + tid], m);
    for (int j = 0; j < m; ++j) {
      int g = base + j;
      if (g < cap) candi[(size_t)(qbase + tid) * cap + g] = sbuf[tid * SDEPTH + j];
    }
  }
}

// ---------------- Kernel 3: select (payload-order agnostic; fp32 rescore) ----------------
__global__ __launch_bounds__(256) void select_kernel(
    const float* __restrict__ keys, const float* __restrict__ tk,
    const float* __restrict__ tv, const int* __restrict__ cnt,
    const unsigned* __restrict__ candi, float* __restrict__ out, int cap) {
  int q = blockIdx.x;
  __shared__ unsigned cvl[CVL];
  __shared__ unsigned hist[NBINS];
  __shared__ unsigned wsum[4];
  __shared__ unsigned minq_sh;
  __shared__ int b50_sh;
  __shared__ int lidx[LW];
  __shared__ unsigned ed2[LW];
  __shared__ int m_sh;
  __shared__ float redw[4], redwv[4];
  int tid = threadIdx.x;
  int lane = tid & 63;
  int wid = tid >> 6;
  int n = cnt[q];
  if (n > cap) n = cap;
  hist[tid] = 0u;
  if (tid == 0) { minq_sh = 0xffffffffu; b50_sh = NBINS - 1; m_sh = 0; }
  __syncthreads();
  const unsigned* cv = candi + (size_t)q * cap;
  unsigned mn = 0xffffffffu;
  for (int i = tid; i < n; i += 256) {
    unsigned v = cv[i];
    if (i < CVL) cvl[i] = v;
    unsigned d = v >> 19; if (d < mn) mn = d;
  }
  #pragma unroll
  for (int off = 1; off < 64; off <<= 1) { unsigned o = __shfl_xor(mn, off); if (o < mn) mn = o; }
  if (lane == 0) atomicMin(&minq_sh, mn);
  __syncthreads();
  unsigned base = minq_sh;
  for (int i = tid; i < n; i += 256) {
    unsigned v = (i < CVL) ? cvl[i] : cv[i];
    unsigned d = (v >> 19) - base;
    unsigned b = d >> 1; if (b > NBINS - 1) b = NBINS - 1;
    atomicAdd(&hist[b], 1u);
  }
  __syncthreads();
  unsigned h = hist[tid];
  unsigned p = h;
  #pragma unroll
  for (int off = 1; off < 64; off <<= 1) {
    unsigned v = __shfl_up(p, off);
    if (lane >= off) p += v;
  }
  if (lane == 63) wsum[wid] = p;
  __syncthreads();
  unsigned add = 0;
  for (int w2 = 0; w2 < wid; ++w2) add += wsum[w2];
  p += add;
  if (p >= (unsigned)K_NEIGH && p - h < (unsigned)K_NEIGH) b50_sh = tid;
  __syncthreads();
  unsigned Tq = base + (((unsigned)(b50_sh + 1)) << 1) + MARGIN_Q;
  for (int i = tid; i < n; i += 256) {
    unsigned v = (i < CVL) ? cvl[i] : cv[i];
    if ((v >> 19) <= Tq) {
      int p2 = atomicAdd(&m_sh, 1);
      if (p2 < LW) lidx[p2] = (int)(v & 0x7ffffu);
    }
  }
  __syncthreads();
  int m = m_sh; if (m > LW) m = LW;
  float kqv = keys[(size_t)q * 64 + lane];
  for (int i0 = wid * 4; i0 < m; i0 += 16) {
    int mm = m - i0; if (mm > 4) mm = 4;
    int idx[4]; float t[4];
    for (int u = 0; u < mm; ++u) idx[u] = lidx[i0 + u];
    for (int u = 0; u < mm; ++u) t[u] = tk[(size_t)idx[u] * 64 + lane];
    for (int u = 0; u < mm; ++u) {
      float d = t[u] - kqv;
      float s = d * d;
      #pragma unroll
      for (int off = 1; off < 64; off <<= 1) s += __shfl_xor(s, off);
      if (lane == 0) ed2[i0 + u] = __float_as_uint(s);
    }
  }
  __syncthreads();
  float accw = 0.f, accwv = 0.f;
  for (int i = tid; i < m; i += 256) {
    unsigned long long key = ((unsigned long long)ed2[i] << 19) | (unsigned)lidx[i];
    int rank = 0;
    for (int j = 0; j < m; ++j) {
      unsigned long long kj = ((unsigned long long)ed2[j] << 19) | (unsigned)lidx[j];
      rank += (kj < key) ? 1 : 0;
    }
    if (rank < K_NEIGH) {
      float d2 = __uint_as_float(ed2[i]);
      float w = 1.f / (d2 + DELTA_SMOOTH);
      accw += w;
      accwv += w * tv[lidx[i]];
    }
  }
  #pragma unroll
  for (int off = 1; off < 64; off <<= 1) {
    accw += __shfl_xor(accw, off);
    accwv += __shfl_xor(accwv, off);
  }
  if (lane == 0) { redw[wid] = accw; redwv[wid] = accwv; }
  __syncthreads();
  if (tid == 0) {
    float sw = redw[0] + redw[1] + redw[2] + redw[3];
    float swv = redwv[0] + redwv[1] + redwv[2] + redwv[3];
    out[q] = swv / sw;
  }
}

extern "C" void kernel_launch(void* const* d_in, const int* in_sizes, int n_in,
                              void* d_out, int out_size, void* d_ws, size_t ws_size,
                              hipStream_t stream) {
  const float* keys = (const float*)d_in[0];   // [B,64]
  const float* tk   = (const float*)d_in[1];   // [C,64]
  const float* tv   = (const float*)d_in[2];   // [C]
  float* out = (float*)d_out;
  int B = in_sizes[0] / 64;   // 1024
  int C = in_sizes[2];        // 500000 (< 2^19 for packing)

  int nchunks = (C + RPB - 1) / RPB;
  int padded = nchunks * RPB;

  char* w = (char*)d_ws;
  float* thrh = (float*)w;  w += (size_t)B * 4;   // fast: thr/2 | fb: thr
  float* qnfb = (float*)w;  w += (size_t)B * 4;   // fallback qn
  int*   cnt  = (int*)w;    w += (size_t)B * 4;
  size_t fixed = (size_t)(w - (char*)d_ws);

  size_t tk_bytes = (size_t)padded * 128 + (size_t)padded * 4;
  size_t dsamp_bytes = (size_t)S_SAMP * (size_t)B * 2;   // 16.8 MB
  size_t region = ws_size > fixed + tk_bytes ? ws_size - fixed - tk_bytes : 0;
  bool fast = region >= dsamp_bytes && region >= 2048ull * (size_t)B * 4;

  if (fast) {
    uint4* tkbf = (uint4*)w;              w += (size_t)padded * 128;
    float* tnh2 = (float*)w;              w += (size_t)padded * 4;
    // dsamp and candi alias the same region (sequential lifetimes)
    unsigned short* dsamp = (unsigned short*)w;
    unsigned* candi = (unsigned*)w;
    int cap = (int)(region / (4ull * (size_t)B));
    if (cap > MAXCAP) cap = MAXCAP;
    int convB = (padded * 8 + 511) / 512;
    int qthB = (S_SAMP / 64) * 2;   // 256
    convert_qthresh<<<convB + qthB, 512, 0, stream>>>(tk, tkbf, tnh2, keys,
                                                      dsamp, C, padded, convB);
    qthresh_scan<<<B, 256, 0, stream>>>(dsamp, thrh, cnt);   // also zeros cnt
    filter_mfma_fast<<<nchunks * 2, 512, 0, stream>>>(tkbf, keys, tnh2, thrh,
                                                      cnt, candi, C, cap);
    select_kernel<<<B, 256, 0, stream>>>(keys, tk, tv, cnt, candi, out, cap);
  } else {
    unsigned* candi = (unsigned*)w;
    int cap = (int)((ws_size - fixed) / (4ull * (size_t)B));
    if (cap > MAXCAP) cap = MAXCAP;
    if (cap < 1) cap = 1;
    hipMemsetAsync(cnt, 0, (size_t)B * 4, stream);
    qthresh_fb<<<B / FQB, 256, 0, stream>>>(keys, tk, thrh, qnfb, C);
    filter_fb<<<nchunks * 2, 512, 0, stream>>>(keys, tk, thrh, qnfb,
                                               cnt, candi, C, cap);
    select_kernel<<<B, 256, 0, stream>>>(keys, tk, tv, cnt, candi, out, cap);
  }
}